// Round 1
// baseline (3223.064 us; speedup 1.0000x reference)
//
#include <hip/hip_runtime.h>
#include <stdint.h>

// Problem constants (fixed by setup_inputs: B=16, A=9, H=W=192)
#define A_NUM   9
#define W_FEAT  192
#define H_FEAT  192
#define K_FEAT  (W_FEAT * H_FEAT)     // 36864 positions
#define N_ANCH  (K_FEAT * A_NUM)      // 331776 anchors per batch
#define PRE_NMS 6000
#define POST_NMS 300
#define CAP     8192                  // candidate buffer / bitonic size (64KB LDS)
#define NBIN    65536                 // histogram bins over top-16 key bits

// py-faster-rcnn standard anchors (base 16, ratios .5/1/2, scales 8/16/32)
__constant__ float c_anchors[A_NUM][4] = {
    { -84.f,  -40.f,  99.f,  55.f},
    {-176.f,  -88.f, 191.f, 103.f},
    {-360.f, -184.f, 375.f, 199.f},
    { -56.f,  -56.f,  71.f,  71.f},
    {-120.f, -120.f, 135.f, 135.f},
    {-248.f, -248.f, 263.f, 263.f},
    { -36.f,  -80.f,  51.f,  95.f},
    { -80.f, -168.f,  95.f, 183.f},
    {-168.f, -344.f, 183.f, 359.f},
};

__device__ __forceinline__ unsigned key_bits(float s) {
    unsigned ub = __float_as_uint(s);
    // monotonic float->uint mapping (handles negatives for robustness)
    return (ub & 0x80000000u) ? ~ub : (ub | 0x80000000u);
}

// fg score for (b, a, k): scores[b, A+a, h, w], n = k*A + a
__device__ __forceinline__ float load_fg(const float* __restrict__ scores, int b, int a, int k) {
    return scores[((size_t)(b * 2 * A_NUM + A_NUM + a)) * K_FEAT + k];
}

// --- Pass 1: per-batch histogram of top-16 key bits --------------------------
__global__ void hist_kernel(const float* __restrict__ scores,
                            unsigned* __restrict__ hist) {
    int gid = blockIdx.x * 256 + threadIdx.x;
    if (gid >= 16 * N_ANCH) return;
    int b = gid / N_ANCH;
    int r = gid - b * N_ANCH;
    int a = r / K_FEAT;
    int k = r - a * K_FEAT;           // consecutive gid -> consecutive k (coalesced)
    unsigned ub = key_bits(load_fg(scores, b, a, k));
    atomicAdd(&hist[b * NBIN + (ub >> 16)], 1u);
}

// --- Pass 2: find threshold bin (descending cumulative crosses PRE_NMS) ------
__global__ void scan_kernel(const unsigned* __restrict__ hist,
                            unsigned* __restrict__ tbin) {
    int b = blockIdx.x;
    __shared__ unsigned csum[256];
    const unsigned* h = hist + (size_t)b * NBIN;
    unsigned s = 0;
    int base = threadIdx.x * 256;
    for (int i = 0; i < 256; ++i) s += h[base + i];
    csum[threadIdx.x] = s;
    __syncthreads();
    if (threadIdx.x == 0) {
        unsigned acc = 0;
        int t = 0;
        for (int c = 255; c >= 0; --c) {
            if (acc + csum[c] >= PRE_NMS) {
                for (int bin = c * 256 + 255; bin >= c * 256; --bin) {
                    unsigned hv = h[bin];
                    if (acc + hv >= PRE_NMS) { t = bin; break; }
                    acc += hv;
                }
                break;
            }
            acc += csum[c];
        }
        tbin[b] = (unsigned)t;
    }
}

// --- Pass 3: compact candidates with bin >= threshold ------------------------
__global__ void compact_kernel(const float* __restrict__ scores,
                               const unsigned* __restrict__ tbin,
                               unsigned* __restrict__ cnt,
                               unsigned long long* __restrict__ cand) {
    int gid = blockIdx.x * 256 + threadIdx.x;
    if (gid >= 16 * N_ANCH) return;
    int b = gid / N_ANCH;
    int r = gid - b * N_ANCH;
    int a = r / K_FEAT;
    int k = r - a * K_FEAT;
    unsigned ub = key_bits(load_fg(scores, b, a, k));
    if ((ub >> 16) >= tbin[b]) {
        unsigned n = (unsigned)(k * A_NUM + a);
        unsigned pos = atomicAdd(&cnt[b], 1u);
        if (pos < CAP)
            cand[(size_t)b * CAP + pos] =
                ((unsigned long long)ub << 32) | (unsigned)(~n);
    }
}

// --- Pass 4: bitonic sort 8192 keys in LDS, decode top-6000 boxes ------------
__global__ __launch_bounds__(256) void sort_decode_kernel(
        const unsigned long long* __restrict__ cand,
        const unsigned* __restrict__ cnt,
        const float* __restrict__ deltas,
        const float* __restrict__ im_info,
        float4* __restrict__ boxes) {
    int b = blockIdx.x;
    __shared__ unsigned long long keys[CAP];   // 64 KiB
    unsigned m = cnt[b];
    if (m > CAP) m = CAP;
    for (int i = threadIdx.x; i < CAP; i += 256)
        keys[i] = (i < (int)m) ? cand[(size_t)b * CAP + i] : 0ULL;
    __syncthreads();

    for (unsigned k = 2; k <= CAP; k <<= 1) {
        for (unsigned j = k >> 1; j > 0; j >>= 1) {
            for (unsigned i = threadIdx.x; i < CAP; i += 256) {
                unsigned ixj = i ^ j;
                if (ixj > i) {
                    unsigned long long x = keys[i], y = keys[ixj];
                    bool desc = ((i & k) == 0);
                    if (desc ? (x < y) : (x > y)) { keys[i] = y; keys[ixj] = x; }
                }
            }
            __syncthreads();
        }
    }

    float wmax = im_info[b * 3 + 1] - 1.0f;
    float hmax = im_info[b * 3 + 0] - 1.0f;
    for (int i = threadIdx.x; i < PRE_NMS; i += 256) {
        unsigned long long key = keys[i];
        unsigned n = ~(unsigned)(key & 0xFFFFFFFFull);
        float4 box = make_float4(0.f, 0.f, 0.f, 0.f);
        if (n < N_ANCH) {
            unsigned kk = n / A_NUM, a = n - kk * A_NUM;
            unsigned hh = kk / W_FEAT, ww = kk - hh * W_FEAT;
            size_t dbase = ((size_t)(b * 4 * A_NUM + 4 * a)) * K_FEAT + kk;
            float dx = deltas[dbase];
            float dy = deltas[dbase + (size_t)K_FEAT];
            float dw = deltas[dbase + (size_t)2 * K_FEAT];
            float dh = deltas[dbase + (size_t)3 * K_FEAT];
            float ax1 = c_anchors[a][0] + ww * 16.0f;
            float ay1 = c_anchors[a][1] + hh * 16.0f;
            float ax2 = c_anchors[a][2] + ww * 16.0f;
            float ay2 = c_anchors[a][3] + hh * 16.0f;
            float waf = ax2 - ax1 + 1.0f, haf = ay2 - ay1 + 1.0f;
            float cx = ax1 + 0.5f * waf, cy = ay1 + 0.5f * haf;
            float pcx = dx * waf + cx, pcy = dy * haf + cy;
            float pw = expf(dw) * waf, ph = expf(dh) * haf;
            float x1 = pcx - 0.5f * pw, y1 = pcy - 0.5f * ph;
            float x2 = pcx + 0.5f * pw, y2 = pcy + 0.5f * ph;
            box.x = fminf(fmaxf(x1, 0.f), wmax);
            box.y = fminf(fmaxf(y1, 0.f), hmax);
            box.z = fminf(fmaxf(x2, 0.f), wmax);
            box.w = fminf(fmaxf(y2, 0.f), hmax);
        }
        boxes[(size_t)b * PRE_NMS + i] = box;
    }
}

// --- Pass 5: greedy NMS (sequential scan == reference argmax loop) -----------
__global__ __launch_bounds__(64) void nms_kernel(const float4* __restrict__ boxes,
                                                 float* __restrict__ out) {
    int b = blockIdx.x;
    int lane = threadIdx.x;
    __shared__ float4 cbuf[64];
    __shared__ float4 kept[POST_NMS];
    __shared__ float karea[POST_NMS];
    const float4* bb = boxes + (size_t)b * PRE_NMS;
    int nk = 0;
    for (int base = 0; base < PRE_NMS && nk < POST_NMS; base += 64) {
        if (base + lane < PRE_NMS) cbuf[lane] = bb[base + lane];
        __syncthreads();
        int lim = min(64, PRE_NMS - base);
        for (int jj = 0; jj < lim; ++jj) {
            float4 cur = cbuf[jj];
            float ca = (cur.z - cur.x + 1.f) * (cur.w - cur.y + 1.f);
            bool sup = false;
            for (int s = lane; s < nk; s += 64) {
                float4 kb = kept[s];
                float xx1 = fmaxf(kb.x, cur.x), yy1 = fmaxf(kb.y, cur.y);
                float xx2 = fminf(kb.z, cur.z), yy2 = fminf(kb.w, cur.w);
                float iw = fmaxf(xx2 - xx1 + 1.f, 0.f);
                float ih = fmaxf(yy2 - yy1 + 1.f, 0.f);
                float inter = iw * ih;
                if (inter > 0.7f * (karea[s] + ca - inter)) sup = true;
            }
            if (!__any(sup)) {
                if (lane == 0) {
                    kept[nk] = cur;
                    karea[nk] = ca;
                    float* o = out + ((size_t)b * POST_NMS + nk) * 5;
                    o[0] = (float)b;
                    o[1] = cur.x; o[2] = cur.y; o[3] = cur.z; o[4] = cur.w;
                }
                ++nk;
                if (nk >= POST_NMS) break;
            }
        }
        __syncthreads();
    }
    // pad remaining rows: [b, 0,0,0,0]
    for (int t = nk + lane; t < POST_NMS; t += 64) {
        float* o = out + ((size_t)b * POST_NMS + t) * 5;
        o[0] = (float)b;
        o[1] = 0.f; o[2] = 0.f; o[3] = 0.f; o[4] = 0.f;
    }
}

extern "C" void kernel_launch(void* const* d_in, const int* in_sizes, int n_in,
                              void* d_out, int out_size, void* d_ws, size_t ws_size,
                              hipStream_t stream) {
    const float* scores  = (const float*)d_in[0];
    const float* deltas  = (const float*)d_in[1];
    const float* im_info = (const float*)d_in[2];
    float* out = (float*)d_out;
    const int B = 16;

    char* ws = (char*)d_ws;
    // layout: hist | cnt | tbin | cand | boxes
    unsigned* hist = (unsigned*)ws;                               // B*NBIN u32
    size_t off = (size_t)B * NBIN * 4;
    unsigned* cnt = (unsigned*)(ws + off);                        // B u32
    size_t zero_bytes = off + (size_t)B * 4;                      // hist + cnt
    off += (size_t)B * 4;
    unsigned* tbin = (unsigned*)(ws + off);                       // B u32
    off += (size_t)B * 4;
    off = (off + 255) & ~(size_t)255;
    unsigned long long* cand = (unsigned long long*)(ws + off);   // B*CAP u64
    off += (size_t)B * CAP * 8;
    off = (off + 255) & ~(size_t)255;
    float4* boxes = (float4*)(ws + off);                          // B*PRE_NMS float4

    hipMemsetAsync(ws, 0, zero_bytes, stream);

    const int total = B * N_ANCH;
    const int nblk = (total + 255) / 256;
    hist_kernel<<<nblk, 256, 0, stream>>>(scores, hist);
    scan_kernel<<<B, 256, 0, stream>>>(hist, tbin);
    compact_kernel<<<nblk, 256, 0, stream>>>(scores, tbin, cnt, cand);
    sort_decode_kernel<<<B, 256, 0, stream>>>(cand, cnt, deltas, im_info, boxes);
    nms_kernel<<<B, 64, 0, stream>>>(boxes, out);
}

// Round 2
// 447.539 us; speedup vs baseline: 7.2017x; 7.2017x over previous
//
#include <hip/hip_runtime.h>
#include <stdint.h>

// Problem constants (fixed by setup_inputs: B=16, A=9, H=W=192)
#define A_NUM    9
#define W_FEAT   192
#define H_FEAT   192
#define K_FEAT   (W_FEAT * H_FEAT)     // 36864 positions
#define N_ANCH   (K_FEAT * A_NUM)      // 331776 anchors per batch
#define BATCH    16
#define PRE_NMS  6000
#define POST_NMS 300
#define CAP      8192                  // candidate buffer / bitonic size (64KB LDS)
#define CHUNK    4096                  // elements per block for hist/compact
#define BPB      (N_ANCH / CHUNK)      // 81 blocks per batch (exact)
#define CPA      (K_FEAT / CHUNK)      // 9 chunks per anchor-plane (exact)
#define SBUF_CAP 1024                  // per-block candidate staging (mean ~91)

// py-faster-rcnn standard anchors (base 16, ratios .5/1/2, scales 8/16/32)
__constant__ float c_anchors[A_NUM][4] = {
    { -84.f,  -40.f,  99.f,  55.f},
    {-176.f,  -88.f, 191.f, 103.f},
    {-360.f, -184.f, 375.f, 199.f},
    { -56.f,  -56.f,  71.f,  71.f},
    {-120.f, -120.f, 135.f, 135.f},
    {-248.f, -248.f, 263.f, 263.f},
    { -36.f,  -80.f,  51.f,  95.f},
    { -80.f, -168.f,  95.f, 183.f},
    {-168.f, -344.f, 183.f, 359.f},
};

__device__ __forceinline__ unsigned key_bits(float s) {
    unsigned ub = __float_as_uint(s);
    return (ub & 0x80000000u) ? ~ub : (ub | 0x80000000u);
}

// Decompose block id -> (batch, a-plane, k-offset); each chunk sits inside one
// (b, a) score plane so loads are fully coalesced.
__device__ __forceinline__ const float* chunk_ptr(const float* scores, int blk,
                                                  int& b, int& a, int& koff) {
    b = blk / BPB;
    int chunk = blk - b * BPB;
    a = chunk / CPA;
    koff = (chunk - a * CPA) * CHUNK;
    return scores + ((size_t)(b * 2 * A_NUM + A_NUM + a)) * K_FEAT + koff;
}

// --- Pass 1a: per-batch 256-bin histogram of top-8 key bits (LDS private) ----
__global__ __launch_bounds__(256) void histA_kernel(const float* __restrict__ scores,
                                                    unsigned* __restrict__ histA) {
    __shared__ unsigned lh[4][256];        // per-wave sub-histograms
    int tid = threadIdx.x;
    for (int w = 0; w < 4; ++w) lh[w][tid] = 0;
    __syncthreads();
    int b, a, koff;
    const float* p = chunk_ptr(scores, blockIdx.x, b, a, koff);
    int wv = tid >> 6;
    #pragma unroll
    for (int it = 0; it < CHUNK / 256; ++it) {
        unsigned ub = key_bits(p[it * 256 + tid]);
        atomicAdd(&lh[wv][ub >> 24], 1u);
    }
    __syncthreads();
    unsigned s = lh[0][tid] + lh[1][tid] + lh[2][tid] + lh[3][tid];
    if (s) atomicAdd(&histA[b * 256 + tid], s);
}

// --- Pass 1b: find top-8 threshold digit ------------------------------------
__global__ void scanA_kernel(const unsigned* __restrict__ histA,
                             unsigned* __restrict__ d8,
                             unsigned* __restrict__ aboveA) {
    int b = blockIdx.x;
    __shared__ unsigned h[256];
    h[threadIdx.x] = histA[b * 256 + threadIdx.x];
    __syncthreads();
    if (threadIdx.x == 0) {
        unsigned acc = 0; int d = 0;
        for (int i = 255; i >= 0; --i) {
            unsigned v = h[i];
            if (acc + v >= PRE_NMS) { d = i; break; }
            acc += v;
        }
        d8[b] = (unsigned)d;
        aboveA[b] = acc;
    }
}

// --- Pass 2a: refine next 8 bits among values with top-8 == d8 ---------------
__global__ __launch_bounds__(256) void histB_kernel(const float* __restrict__ scores,
                                                    const unsigned* __restrict__ d8,
                                                    unsigned* __restrict__ histB) {
    __shared__ unsigned lh[4][256];
    int tid = threadIdx.x;
    for (int w = 0; w < 4; ++w) lh[w][tid] = 0;
    __syncthreads();
    int b, a, koff;
    const float* p = chunk_ptr(scores, blockIdx.x, b, a, koff);
    unsigned d = d8[b];
    int wv = tid >> 6;
    #pragma unroll
    for (int it = 0; it < CHUNK / 256; ++it) {
        unsigned ub = key_bits(p[it * 256 + tid]);
        if ((ub >> 24) == d) atomicAdd(&lh[wv][(ub >> 16) & 0xFF], 1u);
    }
    __syncthreads();
    unsigned s = lh[0][tid] + lh[1][tid] + lh[2][tid] + lh[3][tid];
    if (s) atomicAdd(&histB[b * 256 + tid], s);
}

// --- Pass 2b: final 16-bit threshold ----------------------------------------
__global__ void scanB_kernel(const unsigned* __restrict__ histB,
                             const unsigned* __restrict__ d8,
                             const unsigned* __restrict__ aboveA,
                             unsigned* __restrict__ tbin) {
    int b = blockIdx.x;
    __shared__ unsigned h[256];
    h[threadIdx.x] = histB[b * 256 + threadIdx.x];
    __syncthreads();
    if (threadIdx.x == 0) {
        unsigned acc = aboveA[b]; int d = 0;
        for (int i = 255; i >= 0; --i) {
            unsigned v = h[i];
            if (acc + v >= PRE_NMS) { d = i; break; }
            acc += v;
        }
        tbin[b] = (d8[b] << 8) | (unsigned)d;
    }
}

// --- Pass 3: compact candidates >= threshold (LDS staged, 1 atomic/block) ----
__global__ __launch_bounds__(256) void compact_kernel(
        const float* __restrict__ scores,
        const unsigned* __restrict__ tbin,
        unsigned* __restrict__ cnt,
        unsigned long long* __restrict__ cand) {
    __shared__ unsigned long long sbuf[SBUF_CAP];
    __shared__ unsigned scount, sbase;
    int tid = threadIdx.x;
    if (tid == 0) scount = 0;
    __syncthreads();
    int b, a, koff;
    const float* p = chunk_ptr(scores, blockIdx.x, b, a, koff);
    unsigned t = tbin[b];
    #pragma unroll
    for (int it = 0; it < CHUNK / 256; ++it) {
        int idx = it * 256 + tid;
        unsigned ub = key_bits(p[idx]);
        if ((ub >> 16) >= t) {
            unsigned n = (unsigned)((koff + idx) * A_NUM + a);
            unsigned pos = atomicAdd(&scount, 1u);
            if (pos < SBUF_CAP)
                sbuf[pos] = ((unsigned long long)ub << 32) | (unsigned)(~n);
        }
    }
    __syncthreads();
    unsigned c = scount < SBUF_CAP ? scount : SBUF_CAP;
    if (tid == 0) sbase = atomicAdd(&cnt[b], c);
    __syncthreads();
    unsigned gb = sbase;
    for (unsigned i = tid; i < c; i += 256) {
        unsigned pos = gb + i;
        if (pos < CAP) cand[(size_t)b * CAP + pos] = sbuf[i];
    }
}

// --- Pass 4: bitonic sort 8192 keys in LDS, decode top-6000 boxes ------------
__global__ __launch_bounds__(512) void sort_decode_kernel(
        const unsigned long long* __restrict__ cand,
        const unsigned* __restrict__ cnt,
        const float* __restrict__ deltas,
        const float* __restrict__ im_info,
        float4* __restrict__ boxes) {
    int b = blockIdx.x;
    __shared__ unsigned long long keys[CAP];   // 64 KiB
    unsigned m = cnt[b];
    if (m > CAP) m = CAP;
    for (int i = threadIdx.x; i < CAP; i += 512)
        keys[i] = (i < (int)m) ? cand[(size_t)b * CAP + i] : 0ULL;
    __syncthreads();

    for (unsigned k = 2; k <= CAP; k <<= 1) {
        for (unsigned j = k >> 1; j > 0; j >>= 1) {
            for (unsigned i = threadIdx.x; i < CAP; i += 512) {
                unsigned ixj = i ^ j;
                if (ixj > i) {
                    unsigned long long x = keys[i], y = keys[ixj];
                    bool desc = ((i & k) == 0);
                    if (desc ? (x < y) : (x > y)) { keys[i] = y; keys[ixj] = x; }
                }
            }
            __syncthreads();
        }
    }

    float wmax = im_info[b * 3 + 1] - 1.0f;
    float hmax = im_info[b * 3 + 0] - 1.0f;
    for (int i = threadIdx.x; i < PRE_NMS; i += 512) {
        unsigned long long key = keys[i];
        unsigned n = ~(unsigned)(key & 0xFFFFFFFFull);
        float4 box = make_float4(0.f, 0.f, 0.f, 0.f);
        if (n < N_ANCH) {
            unsigned kk = n / A_NUM, a = n - kk * A_NUM;
            unsigned hh = kk / W_FEAT, ww = kk - hh * W_FEAT;
            size_t dbase = ((size_t)(b * 4 * A_NUM + 4 * a)) * K_FEAT + kk;
            float dx = deltas[dbase];
            float dy = deltas[dbase + (size_t)K_FEAT];
            float dw = deltas[dbase + (size_t)2 * K_FEAT];
            float dh = deltas[dbase + (size_t)3 * K_FEAT];
            float ax1 = c_anchors[a][0] + ww * 16.0f;
            float ay1 = c_anchors[a][1] + hh * 16.0f;
            float ax2 = c_anchors[a][2] + ww * 16.0f;
            float ay2 = c_anchors[a][3] + hh * 16.0f;
            float waf = ax2 - ax1 + 1.0f, haf = ay2 - ay1 + 1.0f;
            float cx = ax1 + 0.5f * waf, cy = ay1 + 0.5f * haf;
            float pcx = dx * waf + cx, pcy = dy * haf + cy;
            float pw = expf(dw) * waf, ph = expf(dh) * haf;
            float x1 = pcx - 0.5f * pw, y1 = pcy - 0.5f * ph;
            float x2 = pcx + 0.5f * pw, y2 = pcy + 0.5f * ph;
            box.x = fminf(fmaxf(x1, 0.f), wmax);
            box.y = fminf(fmaxf(y1, 0.f), hmax);
            box.z = fminf(fmaxf(x2, 0.f), wmax);
            box.w = fminf(fmaxf(y2, 0.f), hmax);
        }
        boxes[(size_t)b * PRE_NMS + i] = box;
    }
}

// --- Pass 5: greedy NMS (sequential scan == reference argmax loop) -----------
__global__ __launch_bounds__(64) void nms_kernel(const float4* __restrict__ boxes,
                                                 float* __restrict__ out) {
    int b = blockIdx.x;
    int lane = threadIdx.x;
    __shared__ float4 cbuf[64];
    __shared__ float4 kept[POST_NMS];
    __shared__ float karea[POST_NMS];
    const float4* bb = boxes + (size_t)b * PRE_NMS;
    int nk = 0;
    for (int base = 0; base < PRE_NMS && nk < POST_NMS; base += 64) {
        if (base + lane < PRE_NMS) cbuf[lane] = bb[base + lane];
        __syncthreads();
        int lim = min(64, PRE_NMS - base);
        for (int jj = 0; jj < lim; ++jj) {
            float4 cur = cbuf[jj];
            float ca = (cur.z - cur.x + 1.f) * (cur.w - cur.y + 1.f);
            bool sup = false;
            for (int s = lane; s < nk; s += 64) {
                float4 kb = kept[s];
                float xx1 = fmaxf(kb.x, cur.x), yy1 = fmaxf(kb.y, cur.y);
                float xx2 = fminf(kb.z, cur.z), yy2 = fminf(kb.w, cur.w);
                float iw = fmaxf(xx2 - xx1 + 1.f, 0.f);
                float ih = fmaxf(yy2 - yy1 + 1.f, 0.f);
                float inter = iw * ih;
                if (inter > 0.7f * (karea[s] + ca - inter)) sup = true;
            }
            if (!__any(sup)) {
                if (lane == 0) {
                    kept[nk] = cur;
                    karea[nk] = ca;
                    float* o = out + ((size_t)b * POST_NMS + nk) * 5;
                    o[0] = (float)b;
                    o[1] = cur.x; o[2] = cur.y; o[3] = cur.z; o[4] = cur.w;
                }
                ++nk;
                if (nk >= POST_NMS) break;
            }
        }
        __syncthreads();
    }
    for (int t = nk + lane; t < POST_NMS; t += 64) {
        float* o = out + ((size_t)b * POST_NMS + t) * 5;
        o[0] = (float)b;
        o[1] = 0.f; o[2] = 0.f; o[3] = 0.f; o[4] = 0.f;
    }
}

extern "C" void kernel_launch(void* const* d_in, const int* in_sizes, int n_in,
                              void* d_out, int out_size, void* d_ws, size_t ws_size,
                              hipStream_t stream) {
    const float* scores  = (const float*)d_in[0];
    const float* deltas  = (const float*)d_in[1];
    const float* im_info = (const float*)d_in[2];
    float* out = (float*)d_out;

    unsigned* histA  = (unsigned*)d_ws;                 // 16*256
    unsigned* histB  = histA + BATCH * 256;             // 16*256
    unsigned* cnt    = histB + BATCH * 256;             // 16
    unsigned* d8     = cnt + BATCH;                     // 16
    unsigned* aboveA = d8 + BATCH;                      // 16
    unsigned* tbin   = aboveA + BATCH;                  // 16
    size_t off = (char*)(tbin + BATCH) - (char*)d_ws;
    off = (off + 255) & ~(size_t)255;
    unsigned long long* cand = (unsigned long long*)((char*)d_ws + off);
    off += (size_t)BATCH * CAP * 8;
    off = (off + 255) & ~(size_t)255;
    float4* boxes = (float4*)((char*)d_ws + off);       // B*PRE_NMS float4

    // zero: histA + histB + cnt (contiguous at the front)
    size_t zero_bytes = (size_t)(2 * BATCH * 256 + BATCH) * 4;
    hipMemsetAsync(d_ws, 0, zero_bytes, stream);

    const int nblk = BATCH * BPB;   // 1296
    histA_kernel  <<<nblk, 256, 0, stream>>>(scores, histA);
    scanA_kernel  <<<BATCH, 256, 0, stream>>>(histA, d8, aboveA);
    histB_kernel  <<<nblk, 256, 0, stream>>>(scores, d8, histB);
    scanB_kernel  <<<BATCH, 256, 0, stream>>>(histB, d8, aboveA, tbin);
    compact_kernel<<<nblk, 256, 0, stream>>>(scores, tbin, cnt, cand);
    sort_decode_kernel<<<BATCH, 512, 0, stream>>>(cand, cnt, deltas, im_info, boxes);
    nms_kernel    <<<BATCH, 64, 0, stream>>>(boxes, out);
}

// Round 3
// 261.006 us; speedup vs baseline: 12.3486x; 1.7147x over previous
//
#include <hip/hip_runtime.h>
#include <stdint.h>

// Problem constants (fixed by setup_inputs: B=16, A=9, H=W=192)
#define A_NUM    9
#define W_FEAT   192
#define H_FEAT   192
#define K_FEAT   (W_FEAT * H_FEAT)     // 36864 positions
#define N_ANCH   (K_FEAT * A_NUM)      // 331776 anchors per batch
#define BATCH    16
#define PRE_NMS  6000
#define POST_NMS 300
#define CAP      8192                  // full candidate buffer (above tbin)
#define CHUNK    4096                  // elements per block for hist/compact
#define BPB      (N_ANCH / CHUNK)      // 81 blocks per batch
#define CPA      (K_FEAT / CHUNK)      // 9 chunks per anchor-plane
#define SBUF_CAP 1024                  // per-block candidate staging (mean ~91)
#define T2TGT    700                   // fast-path candidate target
#define SORT2    2048                  // fast-path sort size (m2 <= ~2000)

// py-faster-rcnn standard anchors (base 16, ratios .5/1/2, scales 8/16/32)
__constant__ float c_anchors[A_NUM][4] = {
    { -84.f,  -40.f,  99.f,  55.f},
    {-176.f,  -88.f, 191.f, 103.f},
    {-360.f, -184.f, 375.f, 199.f},
    { -56.f,  -56.f,  71.f,  71.f},
    {-120.f, -120.f, 135.f, 135.f},
    {-248.f, -248.f, 263.f, 263.f},
    { -36.f,  -80.f,  51.f,  95.f},
    { -80.f, -168.f,  95.f, 183.f},
    {-168.f, -344.f, 183.f, 359.f},
};

__device__ __forceinline__ unsigned key_bits(float s) {
    unsigned ub = __float_as_uint(s);
    return (ub & 0x80000000u) ? ~ub : (ub | 0x80000000u);
}

// chunk -> (batch, anchor-plane, k-offset); chunk fits inside one (b,a) plane
__device__ __forceinline__ const float* chunk_ptr(const float* scores, int blk,
                                                  int& b, int& a, int& koff) {
    b = blk / BPB;
    int chunk = blk - b * BPB;
    a = chunk / CPA;
    koff = (chunk - a * CPA) * CHUNK;
    return scores + ((size_t)(b * 2 * A_NUM + A_NUM + a)) * K_FEAT + koff;
}

// ballot-aggregated LDS histogram add: one atomic per distinct bin per wave
__device__ __forceinline__ void hist_add(unsigned* lh, unsigned bin) {
    unsigned long long peers = __ballot(1);
    #pragma unroll
    for (int bit = 0; bit < 8; ++bit) {
        unsigned long long vote = __ballot((bin >> bit) & 1);
        peers &= ((bin >> bit) & 1) ? vote : ~vote;
    }
    int lane = threadIdx.x & 63;
    if (lane == (int)(__ffsll((long long)peers) - 1))
        atomicAdd(&lh[bin], (unsigned)__popcll(peers));
}

// decode candidate n -> clipped box
__device__ __forceinline__ float4 decode_box(unsigned n, const float* __restrict__ deltas,
                                             int b, float wmax, float hmax) {
    unsigned kk = n / A_NUM, a = n - kk * A_NUM;
    unsigned hh = kk / W_FEAT, ww = kk - hh * W_FEAT;
    size_t dbase = ((size_t)(b * 4 * A_NUM + 4 * a)) * K_FEAT + kk;
    float dx = deltas[dbase];
    float dy = deltas[dbase + (size_t)K_FEAT];
    float dw = deltas[dbase + (size_t)2 * K_FEAT];
    float dh = deltas[dbase + (size_t)3 * K_FEAT];
    float ax1 = c_anchors[a][0] + ww * 16.0f;
    float ay1 = c_anchors[a][1] + hh * 16.0f;
    float ax2 = c_anchors[a][2] + ww * 16.0f;
    float ay2 = c_anchors[a][3] + hh * 16.0f;
    float waf = ax2 - ax1 + 1.0f, haf = ay2 - ay1 + 1.0f;
    float cx = ax1 + 0.5f * waf, cy = ay1 + 0.5f * haf;
    float pcx = dx * waf + cx, pcy = dy * haf + cy;
    float pw = expf(dw) * waf, ph = expf(dh) * haf;
    float4 box;
    box.x = fminf(fmaxf(pcx - 0.5f * pw, 0.f), wmax);
    box.y = fminf(fmaxf(pcy - 0.5f * ph, 0.f), hmax);
    box.z = fminf(fmaxf(pcx + 0.5f * pw, 0.f), wmax);
    box.w = fminf(fmaxf(pcy + 0.5f * ph, 0.f), hmax);
    return box;
}

// --- Pass 1a: per-batch 256-bin histogram of top-8 key bits ------------------
__global__ __launch_bounds__(256) void histA_kernel(const float* __restrict__ scores,
                                                    unsigned* __restrict__ histA) {
    __shared__ unsigned lh[256];
    int tid = threadIdx.x;
    lh[tid] = 0;
    __syncthreads();
    int b, a, koff;
    const float* p = chunk_ptr(scores, blockIdx.x, b, a, koff);
    const float4* p4 = (const float4*)p;
    #pragma unroll
    for (int it = 0; it < CHUNK / 1024; ++it) {
        float4 v = p4[it * 256 + tid];
        hist_add(lh, key_bits(v.x) >> 24);
        hist_add(lh, key_bits(v.y) >> 24);
        hist_add(lh, key_bits(v.z) >> 24);
        hist_add(lh, key_bits(v.w) >> 24);
    }
    __syncthreads();
    if (lh[tid]) atomicAdd(&histA[b * 256 + tid], lh[tid]);
}

// --- Pass 1b: top-8 threshold digit ------------------------------------------
__global__ void scanA_kernel(const unsigned* __restrict__ histA,
                             unsigned* __restrict__ d8,
                             unsigned* __restrict__ aboveA) {
    int b = blockIdx.x;
    __shared__ unsigned h[256];
    h[threadIdx.x] = histA[b * 256 + threadIdx.x];
    __syncthreads();
    if (threadIdx.x == 0) {
        unsigned acc = 0; int d = 0;
        for (int i = 255; i >= 0; --i) {
            unsigned v = h[i];
            if (acc + v >= PRE_NMS) { d = i; break; }
            acc += v;
        }
        d8[b] = (unsigned)d;
        aboveA[b] = acc;
    }
}

// --- Pass 2a: refine next 8 bits among values with top-8 == d8 ---------------
__global__ __launch_bounds__(256) void histB_kernel(const float* __restrict__ scores,
                                                    const unsigned* __restrict__ d8,
                                                    unsigned* __restrict__ histB) {
    __shared__ unsigned lh[256];
    int tid = threadIdx.x;
    lh[tid] = 0;
    __syncthreads();
    int b, a, koff;
    const float* p = chunk_ptr(scores, blockIdx.x, b, a, koff);
    unsigned d = d8[b];
    const float4* p4 = (const float4*)p;
    #pragma unroll
    for (int it = 0; it < CHUNK / 1024; ++it) {
        float4 v = p4[it * 256 + tid];
        unsigned u0 = key_bits(v.x), u1 = key_bits(v.y);
        unsigned u2 = key_bits(v.z), u3 = key_bits(v.w);
        if ((u0 >> 24) == d) hist_add(lh, (u0 >> 16) & 0xFF);
        if ((u1 >> 24) == d) hist_add(lh, (u1 >> 16) & 0xFF);
        if ((u2 >> 24) == d) hist_add(lh, (u2 >> 16) & 0xFF);
        if ((u3 >> 24) == d) hist_add(lh, (u3 >> 16) & 0xFF);
    }
    __syncthreads();
    if (lh[tid]) atomicAdd(&histB[b * 256 + tid], lh[tid]);
}

// --- Pass 2b: final 16-bit thresholds (6000-target and fast 700-target) ------
__global__ void scanB_kernel(const unsigned* __restrict__ histB,
                             const unsigned* __restrict__ d8,
                             const unsigned* __restrict__ aboveA,
                             unsigned* __restrict__ tbin,
                             unsigned* __restrict__ tbin2) {
    int b = blockIdx.x;
    __shared__ unsigned h[256];
    h[threadIdx.x] = histB[b * 256 + threadIdx.x];
    __syncthreads();
    if (threadIdx.x == 0) {
        unsigned dd = d8[b];
        unsigned acc = aboveA[b];
        unsigned t2 = 0; bool t2set = false;
        if (acc >= T2TGT) { t2 = (dd + 1) << 8; t2set = true; }
        int d = 0;
        for (int i = 255; i >= 0; --i) {
            unsigned v = h[i];
            if (!t2set && acc + v >= T2TGT) { t2 = (dd << 8) | (unsigned)i; t2set = true; }
            if (acc + v >= PRE_NMS) { d = i; break; }
            acc += v;
        }
        tbin[b] = (dd << 8) | (unsigned)d;
        tbin2[b] = t2set ? t2 : ((dd << 8) | (unsigned)d);
    }
}

// --- Pass 3: compact candidates >= tbin (LDS staged, 1 global atomic/block) --
__global__ __launch_bounds__(256) void compact_kernel(
        const float* __restrict__ scores,
        const unsigned* __restrict__ tbin,
        unsigned* __restrict__ cntpad,
        unsigned long long* __restrict__ cand) {
    __shared__ unsigned long long sbuf[SBUF_CAP];
    __shared__ unsigned scount, sbase;
    int tid = threadIdx.x;
    if (tid == 0) scount = 0;
    __syncthreads();
    int b, a, koff;
    const float* p = chunk_ptr(scores, blockIdx.x, b, a, koff);
    unsigned t = tbin[b];
    const float4* p4 = (const float4*)p;
    #pragma unroll
    for (int it = 0; it < CHUNK / 1024; ++it) {
        float4 v = p4[it * 256 + tid];
        unsigned e0 = (unsigned)(koff + (it * 256 + tid) * 4);
        float vv[4] = {v.x, v.y, v.z, v.w};
        #pragma unroll
        for (int j = 0; j < 4; ++j) {
            unsigned ub = key_bits(vv[j]);
            if ((ub >> 16) >= t) {
                unsigned n = (e0 + j) * A_NUM + a;
                unsigned pos = atomicAdd(&scount, 1u);
                if (pos < SBUF_CAP)
                    sbuf[pos] = ((unsigned long long)ub << 32) | (unsigned)(~n);
            }
        }
    }
    __syncthreads();
    unsigned c = scount < SBUF_CAP ? scount : SBUF_CAP;
    if (tid == 0) sbase = atomicAdd(&cntpad[b << 5], c);
    __syncthreads();
    unsigned gb = sbase;
    for (unsigned i = tid; i < c; i += 256) {
        unsigned pos = gb + i;
        if (pos < CAP) cand[(size_t)b * CAP + pos] = sbuf[i];
    }
}

// --- Pass 4 (fast path): filter >= tbin2, sort 2048, decode, NMS — fused -----
__global__ __launch_bounds__(512) void topk_nms_kernel(
        const unsigned long long* __restrict__ cand,
        const unsigned* __restrict__ cntpad,
        const unsigned* __restrict__ tbin2,
        const float* __restrict__ deltas,
        const float* __restrict__ im_info,
        float* __restrict__ out,
        unsigned* __restrict__ need_full) {
    int b = blockIdx.x;
    __shared__ unsigned long long keys[SORT2];   // 16 KB
    __shared__ float4 bx[SORT2];                 // 32 KB
    __shared__ float4 kept_s[POST_NMS];
    __shared__ float karea_s[POST_NMS];
    __shared__ unsigned lcnt;
    int tid = threadIdx.x;
    if (tid == 0) lcnt = 0;
    for (int i = tid; i < SORT2; i += 512) keys[i] = 0ULL;
    __syncthreads();

    unsigned m = cntpad[b << 5];
    if (m > CAP) m = CAP;
    unsigned t2 = tbin2[b];
    for (unsigned i = tid; i < m; i += 512) {
        unsigned long long k64 = cand[(size_t)b * CAP + i];
        if ((unsigned)(k64 >> 48) >= t2) {
            unsigned pos = atomicAdd(&lcnt, 1u);
            if (pos < SORT2) keys[pos] = k64;
        }
    }
    __syncthreads();
    unsigned raw2 = lcnt;
    bool ok = (raw2 <= SORT2);
    unsigned m2 = raw2 > SORT2 ? SORT2 : raw2;

    // bitonic sort SORT2 keys descending; 1024 pairs, 2 per thread, no idle lanes
    for (unsigned k = 2; k <= SORT2; k <<= 1) {
        for (unsigned j = k >> 1; j > 0; j >>= 1) {
            #pragma unroll
            for (int pp = 0; pp < 2; ++pp) {
                unsigned p = (unsigned)tid + (unsigned)pp * 512u;
                unsigned i = ((p & ~(j - 1)) << 1) | (p & (j - 1));
                unsigned ixj = i | j;
                unsigned long long x = keys[i], y = keys[ixj];
                bool desc = ((i & k) == 0);
                if (desc ? (x < y) : (x > y)) { keys[i] = y; keys[ixj] = x; }
            }
            __syncthreads();
        }
    }

    // decode sorted prefix into LDS
    float wmax = im_info[b * 3 + 1] - 1.0f;
    float hmax = im_info[b * 3 + 0] - 1.0f;
    for (unsigned i = tid; i < m2; i += 512) {
        unsigned n = ~(unsigned)(keys[i] & 0xFFFFFFFFull);
        bx[i] = decode_box(n, deltas, b, wmax, hmax);
    }
    __syncthreads();

    if (tid >= 64) return;          // wave 0 does NMS
    int lane = tid;
    if (!ok) { if (lane == 0) need_full[b] = 1u; return; }

    int nk = 0;
    int mm = (int)m2;
    for (int i = 0; i < mm && nk < POST_NMS; ++i) {
        float4 cur = bx[i];
        float ca = (cur.z - cur.x + 1.f) * (cur.w - cur.y + 1.f);
        bool sup = false;
        for (int s = lane; s < nk; s += 64) {
            float4 kb = kept_s[s];
            float xx1 = fmaxf(kb.x, cur.x), yy1 = fmaxf(kb.y, cur.y);
            float xx2 = fminf(kb.z, cur.z), yy2 = fminf(kb.w, cur.w);
            float iw = fmaxf(xx2 - xx1 + 1.f, 0.f);
            float ih = fmaxf(yy2 - yy1 + 1.f, 0.f);
            float inter = iw * ih;
            if (inter > 0.7f * (karea_s[s] + ca - inter)) sup = true;
        }
        if (!__any(sup)) {
            if (lane == 0) {
                kept_s[nk] = cur;
                karea_s[nk] = ca;
                float* o = out + ((size_t)b * POST_NMS + nk) * 5;
                o[0] = (float)b;
                o[1] = cur.x; o[2] = cur.y; o[3] = cur.z; o[4] = cur.w;
            }
            ++nk;
        }
    }
    if (lane == 0) need_full[b] = (nk < POST_NMS) ? 1u : 0u;
    for (int t = nk + lane; t < POST_NMS; t += 64) {
        float* o = out + ((size_t)b * POST_NMS + t) * 5;
        o[0] = (float)b;
        o[1] = 0.f; o[2] = 0.f; o[3] = 0.f; o[4] = 0.f;
    }
}

// --- Fallback A: full 8192 bitonic sort + decode (gated, normally no-op) -----
__global__ __launch_bounds__(512) void fb_sort_kernel(
        const unsigned long long* __restrict__ cand,
        const unsigned* __restrict__ cntpad,
        const unsigned* __restrict__ need_full,
        const float* __restrict__ deltas,
        const float* __restrict__ im_info,
        float4* __restrict__ boxes) {
    int b = blockIdx.x;
    if (!need_full[b]) return;
    __shared__ unsigned long long keys[CAP];   // 64 KB
    unsigned m = cntpad[b << 5];
    if (m > CAP) m = CAP;
    for (int i = threadIdx.x; i < CAP; i += 512)
        keys[i] = (i < (int)m) ? cand[(size_t)b * CAP + i] : 0ULL;
    __syncthreads();
    for (unsigned k = 2; k <= CAP; k <<= 1) {
        for (unsigned j = k >> 1; j > 0; j >>= 1) {
            #pragma unroll
            for (int pp = 0; pp < 8; ++pp) {
                unsigned p = (unsigned)threadIdx.x + (unsigned)pp * 512u;
                unsigned i = ((p & ~(j - 1)) << 1) | (p & (j - 1));
                unsigned ixj = i | j;
                unsigned long long x = keys[i], y = keys[ixj];
                bool desc = ((i & k) == 0);
                if (desc ? (x < y) : (x > y)) { keys[i] = y; keys[ixj] = x; }
            }
            __syncthreads();
        }
    }
    float wmax = im_info[b * 3 + 1] - 1.0f;
    float hmax = im_info[b * 3 + 0] - 1.0f;
    for (int i = threadIdx.x; i < PRE_NMS; i += 512) {
        unsigned n = ~(unsigned)(keys[i] & 0xFFFFFFFFull);
        float4 box = make_float4(0.f, 0.f, 0.f, 0.f);
        if (n < N_ANCH) box = decode_box(n, deltas, b, wmax, hmax);
        boxes[(size_t)b * PRE_NMS + i] = box;
    }
}

// --- Fallback B: full NMS over 6000 (gated, normally no-op) ------------------
__global__ __launch_bounds__(64) void fb_nms_kernel(const float4* __restrict__ boxes,
                                                    const unsigned* __restrict__ need_full,
                                                    float* __restrict__ out) {
    int b = blockIdx.x;
    if (!need_full[b]) return;
    int lane = threadIdx.x;
    __shared__ float4 cbuf[64];
    __shared__ float4 kept[POST_NMS];
    __shared__ float karea[POST_NMS];
    const float4* bb = boxes + (size_t)b * PRE_NMS;
    int nk = 0;
    for (int base = 0; base < PRE_NMS && nk < POST_NMS; base += 64) {
        if (base + lane < PRE_NMS) cbuf[lane] = bb[base + lane];
        __syncthreads();
        int lim = min(64, PRE_NMS - base);
        for (int jj = 0; jj < lim; ++jj) {
            float4 cur = cbuf[jj];
            float ca = (cur.z - cur.x + 1.f) * (cur.w - cur.y + 1.f);
            bool sup = false;
            for (int s = lane; s < nk; s += 64) {
                float4 kb = kept[s];
                float xx1 = fmaxf(kb.x, cur.x), yy1 = fmaxf(kb.y, cur.y);
                float xx2 = fminf(kb.z, cur.z), yy2 = fminf(kb.w, cur.w);
                float iw = fmaxf(xx2 - xx1 + 1.f, 0.f);
                float ih = fmaxf(yy2 - yy1 + 1.f, 0.f);
                float inter = iw * ih;
                if (inter > 0.7f * (karea[s] + ca - inter)) sup = true;
            }
            if (!__any(sup)) {
                if (lane == 0) {
                    kept[nk] = cur;
                    karea[nk] = ca;
                    float* o = out + ((size_t)b * POST_NMS + nk) * 5;
                    o[0] = (float)b;
                    o[1] = cur.x; o[2] = cur.y; o[3] = cur.z; o[4] = cur.w;
                }
                ++nk;
                if (nk >= POST_NMS) break;
            }
        }
        __syncthreads();
    }
    for (int t = nk + lane; t < POST_NMS; t += 64) {
        float* o = out + ((size_t)b * POST_NMS + t) * 5;
        o[0] = (float)b;
        o[1] = 0.f; o[2] = 0.f; o[3] = 0.f; o[4] = 0.f;
    }
}

extern "C" void kernel_launch(void* const* d_in, const int* in_sizes, int n_in,
                              void* d_out, int out_size, void* d_ws, size_t ws_size,
                              hipStream_t stream) {
    const float* scores  = (const float*)d_in[0];
    const float* deltas  = (const float*)d_in[1];
    const float* im_info = (const float*)d_in[2];
    float* out = (float*)d_out;

    unsigned* histA   = (unsigned*)d_ws;                  // 16*256
    unsigned* histB   = histA + BATCH * 256;              // 16*256
    unsigned* cntpad  = histB + BATCH * 256;              // 16*32 (cacheline-padded)
    unsigned* d8      = cntpad + BATCH * 32;              // 16
    unsigned* aboveA  = d8 + BATCH;                       // 16
    unsigned* tbin    = aboveA + BATCH;                   // 16
    unsigned* tbin2   = tbin + BATCH;                     // 16
    unsigned* need_fl = tbin2 + BATCH;                    // 16
    size_t off = (char*)(need_fl + BATCH) - (char*)d_ws;
    off = (off + 255) & ~(size_t)255;
    unsigned long long* cand = (unsigned long long*)((char*)d_ws + off);
    off += (size_t)BATCH * CAP * 8;
    off = (off + 255) & ~(size_t)255;
    float4* boxes = (float4*)((char*)d_ws + off);         // fallback only

    // zero: histA + histB + cntpad (contiguous)
    size_t zero_bytes = (size_t)(2 * BATCH * 256 + BATCH * 32) * 4;
    hipMemsetAsync(d_ws, 0, zero_bytes, stream);

    const int nblk = BATCH * BPB;   // 1296
    histA_kernel   <<<nblk, 256, 0, stream>>>(scores, histA);
    scanA_kernel   <<<BATCH, 256, 0, stream>>>(histA, d8, aboveA);
    histB_kernel   <<<nblk, 256, 0, stream>>>(scores, d8, histB);
    scanB_kernel   <<<BATCH, 256, 0, stream>>>(histB, d8, aboveA, tbin, tbin2);
    compact_kernel <<<nblk, 256, 0, stream>>>(scores, tbin, cntpad, cand);
    topk_nms_kernel<<<BATCH, 512, 0, stream>>>(cand, cntpad, tbin2, deltas, im_info,
                                               out, need_fl);
    fb_sort_kernel <<<BATCH, 512, 0, stream>>>(cand, cntpad, need_fl, deltas, im_info, boxes);
    fb_nms_kernel  <<<BATCH, 64, 0, stream>>>(boxes, need_fl, out);
}

// Round 4
// 239.166 us; speedup vs baseline: 13.4763x; 1.0913x over previous
//
#include <hip/hip_runtime.h>
#include <stdint.h>

// Problem constants (fixed by setup_inputs: B=16, A=9, H=W=192)
#define A_NUM    9
#define W_FEAT   192
#define H_FEAT   192
#define K_FEAT   (W_FEAT * H_FEAT)     // 36864 positions
#define N_ANCH   (K_FEAT * A_NUM)      // 331776 anchors per batch
#define BATCH    16
#define PRE_NMS  6000
#define POST_NMS 300
#define CAP      8192                  // full candidate buffer (above tbin)
#define CHUNK    4096                  // elements per block for hist/compact
#define BPB      (N_ANCH / CHUNK)      // 81 blocks per batch
#define CPA      (K_FEAT / CHUNK)      // 9 chunks per anchor-plane
#define SBUF_CAP 1024                  // per-block candidate staging (mean ~91)
#define T2TGT    700                   // fast-path candidate target
#define SORT2    2048                  // fast-path sort size (m2 <= ~2000)

// py-faster-rcnn standard anchors (base 16, ratios .5/1/2, scales 8/16/32)
__constant__ float c_anchors[A_NUM][4] = {
    { -84.f,  -40.f,  99.f,  55.f},
    {-176.f,  -88.f, 191.f, 103.f},
    {-360.f, -184.f, 375.f, 199.f},
    { -56.f,  -56.f,  71.f,  71.f},
    {-120.f, -120.f, 135.f, 135.f},
    {-248.f, -248.f, 263.f, 263.f},
    { -36.f,  -80.f,  51.f,  95.f},
    { -80.f, -168.f,  95.f, 183.f},
    {-168.f, -344.f, 183.f, 359.f},
};

__device__ __forceinline__ unsigned key_bits(float s) {
    unsigned ub = __float_as_uint(s);
    return (ub & 0x80000000u) ? ~ub : (ub | 0x80000000u);
}

// chunk -> (batch, anchor-plane, k-offset); chunk fits inside one (b,a) plane
__device__ __forceinline__ const float* chunk_ptr(const float* scores, int blk,
                                                  int& b, int& a, int& koff) {
    b = blk / BPB;
    int chunk = blk - b * BPB;
    a = chunk / CPA;
    koff = (chunk - a * CPA) * CHUNK;
    return scores + ((size_t)(b * 2 * A_NUM + A_NUM + a)) * K_FEAT + koff;
}

// ballot-aggregated LDS histogram add: one atomic per distinct bin per wave
__device__ __forceinline__ void hist_add(unsigned* lh, unsigned bin) {
    unsigned long long peers = __ballot(1);
    #pragma unroll
    for (int bit = 0; bit < 8; ++bit) {
        unsigned long long vote = __ballot((bin >> bit) & 1);
        peers &= ((bin >> bit) & 1) ? vote : ~vote;
    }
    int lane = threadIdx.x & 63;
    if (lane == (int)(__ffsll((long long)peers) - 1))
        atomicAdd(&lh[bin], (unsigned)__popcll(peers));
}

// decode candidate n -> clipped box
__device__ __forceinline__ float4 decode_box(unsigned n, const float* __restrict__ deltas,
                                             int b, float wmax, float hmax) {
    unsigned kk = n / A_NUM, a = n - kk * A_NUM;
    unsigned hh = kk / W_FEAT, ww = kk - hh * W_FEAT;
    size_t dbase = ((size_t)(b * 4 * A_NUM + 4 * a)) * K_FEAT + kk;
    float dx = deltas[dbase];
    float dy = deltas[dbase + (size_t)K_FEAT];
    float dw = deltas[dbase + (size_t)2 * K_FEAT];
    float dh = deltas[dbase + (size_t)3 * K_FEAT];
    float ax1 = c_anchors[a][0] + ww * 16.0f;
    float ay1 = c_anchors[a][1] + hh * 16.0f;
    float ax2 = c_anchors[a][2] + ww * 16.0f;
    float ay2 = c_anchors[a][3] + hh * 16.0f;
    float waf = ax2 - ax1 + 1.0f, haf = ay2 - ay1 + 1.0f;
    float cx = ax1 + 0.5f * waf, cy = ay1 + 0.5f * haf;
    float pcx = dx * waf + cx, pcy = dy * haf + cy;
    float pw = expf(dw) * waf, ph = expf(dh) * haf;
    float4 box;
    box.x = fminf(fmaxf(pcx - 0.5f * pw, 0.f), wmax);
    box.y = fminf(fmaxf(pcy - 0.5f * ph, 0.f), hmax);
    box.z = fminf(fmaxf(pcx + 0.5f * pw, 0.f), wmax);
    box.w = fminf(fmaxf(pcy + 0.5f * ph, 0.f), hmax);
    return box;
}

// IoU(a, c) > 0.7, same algebra as all prior (passing) rounds
__device__ __forceinline__ bool iou_over(float4 a, float aa, float4 c, float ca) {
    float xx1 = fmaxf(a.x, c.x), yy1 = fmaxf(a.y, c.y);
    float xx2 = fminf(a.z, c.z), yy2 = fminf(a.w, c.w);
    float iw = fmaxf(xx2 - xx1 + 1.f, 0.f);
    float ih = fmaxf(yy2 - yy1 + 1.f, 0.f);
    float inter = iw * ih;
    return inter > 0.7f * (aa + ca - inter);
}

// --- Pass 1a: per-batch 256-bin histogram of top-8 key bits ------------------
__global__ __launch_bounds__(256) void histA_kernel(const float* __restrict__ scores,
                                                    unsigned* __restrict__ histA) {
    __shared__ unsigned lh[256];
    int tid = threadIdx.x;
    lh[tid] = 0;
    __syncthreads();
    int b, a, koff;
    const float* p = chunk_ptr(scores, blockIdx.x, b, a, koff);
    const float4* p4 = (const float4*)p;
    #pragma unroll
    for (int it = 0; it < CHUNK / 1024; ++it) {
        float4 v = p4[it * 256 + tid];
        hist_add(lh, key_bits(v.x) >> 24);
        hist_add(lh, key_bits(v.y) >> 24);
        hist_add(lh, key_bits(v.z) >> 24);
        hist_add(lh, key_bits(v.w) >> 24);
    }
    __syncthreads();
    if (lh[tid]) atomicAdd(&histA[b * 256 + tid], lh[tid]);
}

// --- Pass 1b: top-8 threshold digit ------------------------------------------
__global__ void scanA_kernel(const unsigned* __restrict__ histA,
                             unsigned* __restrict__ d8,
                             unsigned* __restrict__ aboveA) {
    int b = blockIdx.x;
    __shared__ unsigned h[256];
    h[threadIdx.x] = histA[b * 256 + threadIdx.x];
    __syncthreads();
    if (threadIdx.x == 0) {
        unsigned acc = 0; int d = 0;
        for (int i = 255; i >= 0; --i) {
            unsigned v = h[i];
            if (acc + v >= PRE_NMS) { d = i; break; }
            acc += v;
        }
        d8[b] = (unsigned)d;
        aboveA[b] = acc;
    }
}

// --- Pass 2a: refine next 8 bits among values with top-8 == d8 ---------------
__global__ __launch_bounds__(256) void histB_kernel(const float* __restrict__ scores,
                                                    const unsigned* __restrict__ d8,
                                                    unsigned* __restrict__ histB) {
    __shared__ unsigned lh[256];
    int tid = threadIdx.x;
    lh[tid] = 0;
    __syncthreads();
    int b, a, koff;
    const float* p = chunk_ptr(scores, blockIdx.x, b, a, koff);
    unsigned d = d8[b];
    const float4* p4 = (const float4*)p;
    #pragma unroll
    for (int it = 0; it < CHUNK / 1024; ++it) {
        float4 v = p4[it * 256 + tid];
        unsigned u0 = key_bits(v.x), u1 = key_bits(v.y);
        unsigned u2 = key_bits(v.z), u3 = key_bits(v.w);
        if ((u0 >> 24) == d) hist_add(lh, (u0 >> 16) & 0xFF);
        if ((u1 >> 24) == d) hist_add(lh, (u1 >> 16) & 0xFF);
        if ((u2 >> 24) == d) hist_add(lh, (u2 >> 16) & 0xFF);
        if ((u3 >> 24) == d) hist_add(lh, (u3 >> 16) & 0xFF);
    }
    __syncthreads();
    if (lh[tid]) atomicAdd(&histB[b * 256 + tid], lh[tid]);
}

// --- Pass 2b: final 16-bit thresholds (6000-target and fast 700-target) ------
__global__ void scanB_kernel(const unsigned* __restrict__ histB,
                             const unsigned* __restrict__ d8,
                             const unsigned* __restrict__ aboveA,
                             unsigned* __restrict__ tbin,
                             unsigned* __restrict__ tbin2) {
    int b = blockIdx.x;
    __shared__ unsigned h[256];
    h[threadIdx.x] = histB[b * 256 + threadIdx.x];
    __syncthreads();
    if (threadIdx.x == 0) {
        unsigned dd = d8[b];
        unsigned acc = aboveA[b];
        unsigned t2 = 0; bool t2set = false;
        if (acc >= T2TGT) { t2 = (dd + 1) << 8; t2set = true; }
        int d = 0;
        for (int i = 255; i >= 0; --i) {
            unsigned v = h[i];
            if (!t2set && acc + v >= T2TGT) { t2 = (dd << 8) | (unsigned)i; t2set = true; }
            if (acc + v >= PRE_NMS) { d = i; break; }
            acc += v;
        }
        tbin[b] = (dd << 8) | (unsigned)d;
        tbin2[b] = t2set ? t2 : ((dd << 8) | (unsigned)d);
    }
}

// --- Pass 3: compact candidates >= tbin (LDS staged, 1 global atomic/block) --
__global__ __launch_bounds__(256) void compact_kernel(
        const float* __restrict__ scores,
        const unsigned* __restrict__ tbin,
        unsigned* __restrict__ cntpad,
        unsigned long long* __restrict__ cand) {
    __shared__ unsigned long long sbuf[SBUF_CAP];
    __shared__ unsigned scount, sbase;
    int tid = threadIdx.x;
    if (tid == 0) scount = 0;
    __syncthreads();
    int b, a, koff;
    const float* p = chunk_ptr(scores, blockIdx.x, b, a, koff);
    unsigned t = tbin[b];
    const float4* p4 = (const float4*)p;
    #pragma unroll
    for (int it = 0; it < CHUNK / 1024; ++it) {
        float4 v = p4[it * 256 + tid];
        unsigned e0 = (unsigned)(koff + (it * 256 + tid) * 4);
        float vv[4] = {v.x, v.y, v.z, v.w};
        #pragma unroll
        for (int j = 0; j < 4; ++j) {
            unsigned ub = key_bits(vv[j]);
            if ((ub >> 16) >= t) {
                unsigned n = (e0 + j) * A_NUM + a;
                unsigned pos = atomicAdd(&scount, 1u);
                if (pos < SBUF_CAP)
                    sbuf[pos] = ((unsigned long long)ub << 32) | (unsigned)(~n);
            }
        }
    }
    __syncthreads();
    unsigned c = scount < SBUF_CAP ? scount : SBUF_CAP;
    if (tid == 0) sbase = atomicAdd(&cntpad[b << 5], c);
    __syncthreads();
    unsigned gb = sbase;
    for (unsigned i = tid; i < c; i += 256) {
        unsigned pos = gb + i;
        if (pos < CAP) cand[(size_t)b * CAP + pos] = sbuf[i];
    }
}

// --- Pass 4 (fast path): filter >= tbin2, sort 2048, decode, NMS — fused -----
// NMS: kept boxes in registers (lane l owns slots l+64r), prefetched candidates,
// 2-wide speculative rounds. No LDS on the serial chain.
__global__ __launch_bounds__(512) void topk_nms_kernel(
        const unsigned long long* __restrict__ cand,
        const unsigned* __restrict__ cntpad,
        const unsigned* __restrict__ tbin2,
        const float* __restrict__ deltas,
        const float* __restrict__ im_info,
        float* __restrict__ out,
        unsigned* __restrict__ need_full) {
    int b = blockIdx.x;
    __shared__ unsigned long long keys[SORT2];   // 16 KB
    __shared__ float4 bx[SORT2];                 // 32 KB
    __shared__ unsigned lcnt;
    int tid = threadIdx.x;
    if (tid == 0) lcnt = 0;
    for (int i = tid; i < SORT2; i += 512) keys[i] = 0ULL;
    __syncthreads();

    unsigned m = cntpad[b << 5];
    if (m > CAP) m = CAP;
    unsigned t2 = tbin2[b];
    for (unsigned i = tid; i < m; i += 512) {
        unsigned long long k64 = cand[(size_t)b * CAP + i];
        if ((unsigned)(k64 >> 48) >= t2) {
            unsigned pos = atomicAdd(&lcnt, 1u);
            if (pos < SORT2) keys[pos] = k64;
        }
    }
    __syncthreads();
    unsigned raw2 = lcnt;
    bool ok = (raw2 <= SORT2);
    unsigned m2 = raw2 > SORT2 ? SORT2 : raw2;

    // bitonic sort SORT2 keys descending; 1024 pairs, 2 per thread
    for (unsigned k = 2; k <= SORT2; k <<= 1) {
        for (unsigned j = k >> 1; j > 0; j >>= 1) {
            #pragma unroll
            for (int pp = 0; pp < 2; ++pp) {
                unsigned p = (unsigned)tid + (unsigned)pp * 512u;
                unsigned i = ((p & ~(j - 1)) << 1) | (p & (j - 1));
                unsigned ixj = i | j;
                unsigned long long x = keys[i], y = keys[ixj];
                bool desc = ((i & k) == 0);
                if (desc ? (x < y) : (x > y)) { keys[i] = y; keys[ixj] = x; }
            }
            __syncthreads();
        }
    }

    // decode sorted prefix into LDS
    float wmax = im_info[b * 3 + 1] - 1.0f;
    float hmax = im_info[b * 3 + 0] - 1.0f;
    for (unsigned i = tid; i < m2; i += 512) {
        unsigned n = ~(unsigned)(keys[i] & 0xFFFFFFFFull);
        bx[i] = decode_box(n, deltas, b, wmax, hmax);
    }
    __syncthreads();

    if (tid >= 64) return;          // wave 0 does NMS
    int lane = tid;
    if (!ok) { if (lane == 0) need_full[b] = 1u; return; }

    float4 k0, k1v, k2v, k3v, k4v;  // kept slots: lane l owns kept index l + 64*r
    float a0 = 1.f, a1 = 1.f, a2 = 1.f, a3 = 1.f, a4 = 1.f;
    k0 = k1v = k2v = k3v = k4v = make_float4(0.f, 0.f, 0.f, 0.f);

    int nk = 0;
    int mm = (int)m2;
    int i = 0;
    float4 nA = bx[0];
    float4 nB = bx[mm > 1 ? 1 : 0];
    while (i < mm && nk < POST_NMS) {
        float4 c0 = nA, c1 = nB;
        bool have1 = (i + 1 < mm);
        int ip2 = i + 2 < mm ? i + 2 : mm - 1;
        int ip3 = i + 3 < mm ? i + 3 : mm - 1;
        nA = bx[ip2];                // prefetch next round (latency hidden)
        nB = bx[ip3];
        float ca0 = (c0.z - c0.x + 1.f) * (c0.w - c0.y + 1.f);
        float ca1 = (c1.z - c1.x + 1.f) * (c1.w - c1.y + 1.f);
        bool s0 = false, s1 = false;
        if (nk > 0) {
            bool v = lane < nk;
            s0 |= v && iou_over(k0, a0, c0, ca0);
            s1 |= v && iou_over(k0, a0, c1, ca1);
        }
        if (nk > 64) {
            bool v = 64 + lane < nk;
            s0 |= v && iou_over(k1v, a1, c0, ca0);
            s1 |= v && iou_over(k1v, a1, c1, ca1);
        }
        if (nk > 128) {
            bool v = 128 + lane < nk;
            s0 |= v && iou_over(k2v, a2, c0, ca0);
            s1 |= v && iou_over(k2v, a2, c1, ca1);
        }
        if (nk > 192) {
            bool v = 192 + lane < nk;
            s0 |= v && iou_over(k3v, a3, c0, ca0);
            s1 |= v && iou_over(k3v, a3, c1, ca1);
        }
        if (nk > 256) {
            bool v = 256 + lane < nk;
            s0 |= v && iou_over(k4v, a4, c0, ca0);
            s1 |= v && iou_over(k4v, a4, c1, ca1);
        }
        unsigned long long b0 = __ballot(s0);
        unsigned long long b1 = __ballot(s1);
        bool x01 = iou_over(c0, ca0, c1, ca1);
        bool keep0 = (b0 == 0ULL);
        bool keep1 = have1 && (b1 == 0ULL) && !(keep0 && x01);
        if (keep0) {
            int r = nk >> 6;
            if (lane == (nk & 63)) {
                if      (r == 0) { k0  = c0; a0 = ca0; }
                else if (r == 1) { k1v = c0; a1 = ca0; }
                else if (r == 2) { k2v = c0; a2 = ca0; }
                else if (r == 3) { k3v = c0; a3 = ca0; }
                else             { k4v = c0; a4 = ca0; }
            }
            if (lane == 0) {
                float* o = out + ((size_t)b * POST_NMS + nk) * 5;
                o[0] = (float)b;
                o[1] = c0.x; o[2] = c0.y; o[3] = c0.z; o[4] = c0.w;
            }
            ++nk;
        }
        if (keep1 && nk < POST_NMS) {
            int r = nk >> 6;
            if (lane == (nk & 63)) {
                if      (r == 0) { k0  = c1; a0 = ca1; }
                else if (r == 1) { k1v = c1; a1 = ca1; }
                else if (r == 2) { k2v = c1; a2 = ca1; }
                else if (r == 3) { k3v = c1; a3 = ca1; }
                else             { k4v = c1; a4 = ca1; }
            }
            if (lane == 0) {
                float* o = out + ((size_t)b * POST_NMS + nk) * 5;
                o[0] = (float)b;
                o[1] = c1.x; o[2] = c1.y; o[3] = c1.z; o[4] = c1.w;
            }
            ++nk;
        }
        i += 2;
    }
    if (lane == 0) need_full[b] = (nk < POST_NMS) ? 1u : 0u;
    for (int t = nk + lane; t < POST_NMS; t += 64) {
        float* o = out + ((size_t)b * POST_NMS + t) * 5;
        o[0] = (float)b;
        o[1] = 0.f; o[2] = 0.f; o[3] = 0.f; o[4] = 0.f;
    }
}

// --- Fallback A: full 8192 bitonic sort + decode (gated, normally no-op) -----
__global__ __launch_bounds__(512) void fb_sort_kernel(
        const unsigned long long* __restrict__ cand,
        const unsigned* __restrict__ cntpad,
        const unsigned* __restrict__ need_full,
        const float* __restrict__ deltas,
        const float* __restrict__ im_info,
        float4* __restrict__ boxes) {
    int b = blockIdx.x;
    if (!need_full[b]) return;
    __shared__ unsigned long long keys[CAP];   // 64 KB
    unsigned m = cntpad[b << 5];
    if (m > CAP) m = CAP;
    for (int i = threadIdx.x; i < CAP; i += 512)
        keys[i] = (i < (int)m) ? cand[(size_t)b * CAP + i] : 0ULL;
    __syncthreads();
    for (unsigned k = 2; k <= CAP; k <<= 1) {
        for (unsigned j = k >> 1; j > 0; j >>= 1) {
            #pragma unroll
            for (int pp = 0; pp < 8; ++pp) {
                unsigned p = (unsigned)threadIdx.x + (unsigned)pp * 512u;
                unsigned i = ((p & ~(j - 1)) << 1) | (p & (j - 1));
                unsigned ixj = i | j;
                unsigned long long x = keys[i], y = keys[ixj];
                bool desc = ((i & k) == 0);
                if (desc ? (x < y) : (x > y)) { keys[i] = y; keys[ixj] = x; }
            }
            __syncthreads();
        }
    }
    float wmax = im_info[b * 3 + 1] - 1.0f;
    float hmax = im_info[b * 3 + 0] - 1.0f;
    for (int i = threadIdx.x; i < PRE_NMS; i += 512) {
        unsigned n = ~(unsigned)(keys[i] & 0xFFFFFFFFull);
        float4 box = make_float4(0.f, 0.f, 0.f, 0.f);
        if (n < N_ANCH) box = decode_box(n, deltas, b, wmax, hmax);
        boxes[(size_t)b * PRE_NMS + i] = box;
    }
}

// --- Fallback B: full NMS over 6000 (gated, normally no-op) ------------------
__global__ __launch_bounds__(64) void fb_nms_kernel(const float4* __restrict__ boxes,
                                                    const unsigned* __restrict__ need_full,
                                                    float* __restrict__ out) {
    int b = blockIdx.x;
    if (!need_full[b]) return;
    int lane = threadIdx.x;
    __shared__ float4 cbuf[64];
    __shared__ float4 kept[POST_NMS];
    __shared__ float karea[POST_NMS];
    const float4* bb = boxes + (size_t)b * PRE_NMS;
    int nk = 0;
    for (int base = 0; base < PRE_NMS && nk < POST_NMS; base += 64) {
        if (base + lane < PRE_NMS) cbuf[lane] = bb[base + lane];
        __syncthreads();
        int lim = min(64, PRE_NMS - base);
        for (int jj = 0; jj < lim; ++jj) {
            float4 cur = cbuf[jj];
            float ca = (cur.z - cur.x + 1.f) * (cur.w - cur.y + 1.f);
            bool sup = false;
            for (int s = lane; s < nk; s += 64) {
                float4 kb = kept[s];
                float xx1 = fmaxf(kb.x, cur.x), yy1 = fmaxf(kb.y, cur.y);
                float xx2 = fminf(kb.z, cur.z), yy2 = fminf(kb.w, cur.w);
                float iw = fmaxf(xx2 - xx1 + 1.f, 0.f);
                float ih = fmaxf(yy2 - yy1 + 1.f, 0.f);
                float inter = iw * ih;
                if (inter > 0.7f * (karea[s] + ca - inter)) sup = true;
            }
            if (!__any(sup)) {
                if (lane == 0) {
                    kept[nk] = cur;
                    karea[nk] = ca;
                    float* o = out + ((size_t)b * POST_NMS + nk) * 5;
                    o[0] = (float)b;
                    o[1] = cur.x; o[2] = cur.y; o[3] = cur.z; o[4] = cur.w;
                }
                ++nk;
                if (nk >= POST_NMS) break;
            }
        }
        __syncthreads();
    }
    for (int t = nk + lane; t < POST_NMS; t += 64) {
        float* o = out + ((size_t)b * POST_NMS + t) * 5;
        o[0] = (float)b;
        o[1] = 0.f; o[2] = 0.f; o[3] = 0.f; o[4] = 0.f;
    }
}

extern "C" void kernel_launch(void* const* d_in, const int* in_sizes, int n_in,
                              void* d_out, int out_size, void* d_ws, size_t ws_size,
                              hipStream_t stream) {
    const float* scores  = (const float*)d_in[0];
    const float* deltas  = (const float*)d_in[1];
    const float* im_info = (const float*)d_in[2];
    float* out = (float*)d_out;

    unsigned* histA   = (unsigned*)d_ws;                  // 16*256
    unsigned* histB   = histA + BATCH * 256;              // 16*256
    unsigned* cntpad  = histB + BATCH * 256;              // 16*32 (cacheline-padded)
    unsigned* d8      = cntpad + BATCH * 32;              // 16
    unsigned* aboveA  = d8 + BATCH;                       // 16
    unsigned* tbin    = aboveA + BATCH;                   // 16
    unsigned* tbin2   = tbin + BATCH;                     // 16
    unsigned* need_fl = tbin2 + BATCH;                    // 16
    size_t off = (char*)(need_fl + BATCH) - (char*)d_ws;
    off = (off + 255) & ~(size_t)255;
    unsigned long long* cand = (unsigned long long*)((char*)d_ws + off);
    off += (size_t)BATCH * CAP * 8;
    off = (off + 255) & ~(size_t)255;
    float4* boxes = (float4*)((char*)d_ws + off);         // fallback only

    // zero: histA + histB + cntpad (contiguous)
    size_t zero_bytes = (size_t)(2 * BATCH * 256 + BATCH * 32) * 4;
    hipMemsetAsync(d_ws, 0, zero_bytes, stream);

    const int nblk = BATCH * BPB;   // 1296
    histA_kernel   <<<nblk, 256, 0, stream>>>(scores, histA);
    scanA_kernel   <<<BATCH, 256, 0, stream>>>(histA, d8, aboveA);
    histB_kernel   <<<nblk, 256, 0, stream>>>(scores, d8, histB);
    scanB_kernel   <<<BATCH, 256, 0, stream>>>(histB, d8, aboveA, tbin, tbin2);
    compact_kernel <<<nblk, 256, 0, stream>>>(scores, tbin, cntpad, cand);
    topk_nms_kernel<<<BATCH, 512, 0, stream>>>(cand, cntpad, tbin2, deltas, im_info,
                                               out, need_fl);
    fb_sort_kernel <<<BATCH, 512, 0, stream>>>(cand, cntpad, need_fl, deltas, im_info, boxes);
    fb_nms_kernel  <<<BATCH, 64, 0, stream>>>(boxes, need_fl, out);
}

// Round 5
// 215.722 us; speedup vs baseline: 14.9408x; 1.1087x over previous
//
#include <hip/hip_runtime.h>
#include <stdint.h>

// Problem constants (fixed by setup_inputs: B=16, A=9, H=W=192)
#define A_NUM    9
#define W_FEAT   192
#define H_FEAT   192
#define K_FEAT   (W_FEAT * H_FEAT)     // 36864 positions
#define N_ANCH   (K_FEAT * A_NUM)      // 331776 anchors per batch
#define BATCH    16
#define PRE_NMS  6000
#define POST_NMS 300
#define CAP      8192                  // full candidate buffer (above tbin)
#define CHUNK    4096                  // elements per block for hist/compact
#define BPB      (N_ANCH / CHUNK)      // 81 blocks per batch
#define CPA      (K_FEAT / CHUNK)      // 9 chunks per anchor-plane
#define SBUF_CAP 1024                  // per-block candidate staging (mean ~91)
#define T2TGT    700                   // fast-path candidate target
#define SORT2    2048                  // fast-path sort size (m2 <= ~2000)
#define NWORD    (SORT2 / 64)          // 32 mask words per row

// py-faster-rcnn standard anchors (base 16, ratios .5/1/2, scales 8/16/32)
__constant__ float c_anchors[A_NUM][4] = {
    { -84.f,  -40.f,  99.f,  55.f},
    {-176.f,  -88.f, 191.f, 103.f},
    {-360.f, -184.f, 375.f, 199.f},
    { -56.f,  -56.f,  71.f,  71.f},
    {-120.f, -120.f, 135.f, 135.f},
    {-248.f, -248.f, 263.f, 263.f},
    { -36.f,  -80.f,  51.f,  95.f},
    { -80.f, -168.f,  95.f, 183.f},
    {-168.f, -344.f, 183.f, 359.f},
};

__device__ __forceinline__ unsigned key_bits(float s) {
    unsigned ub = __float_as_uint(s);
    return (ub & 0x80000000u) ? ~ub : (ub | 0x80000000u);
}

__device__ __forceinline__ const float* chunk_ptr(const float* scores, int blk,
                                                  int& b, int& a, int& koff) {
    b = blk / BPB;
    int chunk = blk - b * BPB;
    a = chunk / CPA;
    koff = (chunk - a * CPA) * CHUNK;
    return scores + ((size_t)(b * 2 * A_NUM + A_NUM + a)) * K_FEAT + koff;
}

// ballot-aggregated LDS histogram add: one atomic per distinct bin per wave
__device__ __forceinline__ void hist_add(unsigned* lh, unsigned bin) {
    unsigned long long peers = __ballot(1);
    #pragma unroll
    for (int bit = 0; bit < 8; ++bit) {
        unsigned long long vote = __ballot((bin >> bit) & 1);
        peers &= ((bin >> bit) & 1) ? vote : ~vote;
    }
    int lane = threadIdx.x & 63;
    if (lane == (int)(__ffsll((long long)peers) - 1))
        atomicAdd(&lh[bin], (unsigned)__popcll(peers));
}

__device__ __forceinline__ float4 decode_box(unsigned n, const float* __restrict__ deltas,
                                             int b, float wmax, float hmax) {
    unsigned kk = n / A_NUM, a = n - kk * A_NUM;
    unsigned hh = kk / W_FEAT, ww = kk - hh * W_FEAT;
    size_t dbase = ((size_t)(b * 4 * A_NUM + 4 * a)) * K_FEAT + kk;
    float dx = deltas[dbase];
    float dy = deltas[dbase + (size_t)K_FEAT];
    float dw = deltas[dbase + (size_t)2 * K_FEAT];
    float dh = deltas[dbase + (size_t)3 * K_FEAT];
    float ax1 = c_anchors[a][0] + ww * 16.0f;
    float ay1 = c_anchors[a][1] + hh * 16.0f;
    float ax2 = c_anchors[a][2] + ww * 16.0f;
    float ay2 = c_anchors[a][3] + hh * 16.0f;
    float waf = ax2 - ax1 + 1.0f, haf = ay2 - ay1 + 1.0f;
    float cx = ax1 + 0.5f * waf, cy = ay1 + 0.5f * haf;
    float pcx = dx * waf + cx, pcy = dy * haf + cy;
    float pw = expf(dw) * waf, ph = expf(dh) * haf;
    float4 box;
    box.x = fminf(fmaxf(pcx - 0.5f * pw, 0.f), wmax);
    box.y = fminf(fmaxf(pcy - 0.5f * ph, 0.f), hmax);
    box.z = fminf(fmaxf(pcx + 0.5f * pw, 0.f), wmax);
    box.w = fminf(fmaxf(pcy + 0.5f * ph, 0.f), hmax);
    return box;
}

// IoU(a, c) > 0.7 — identical algebra in every consumer (bit-identical decisions)
__device__ __forceinline__ bool iou_over(float4 a, float aa, float4 c, float ca) {
    float xx1 = fmaxf(a.x, c.x), yy1 = fmaxf(a.y, c.y);
    float xx2 = fminf(a.z, c.z), yy2 = fminf(a.w, c.w);
    float iw = fmaxf(xx2 - xx1 + 1.f, 0.f);
    float ih = fmaxf(yy2 - yy1 + 1.f, 0.f);
    float inter = iw * ih;
    return inter > 0.7f * (aa + ca - inter);
}

// --- Pass 1a: per-batch 256-bin histogram of top-8 key bits ------------------
__global__ __launch_bounds__(256) void histA_kernel(const float* __restrict__ scores,
                                                    unsigned* __restrict__ histA) {
    __shared__ unsigned lh[256];
    int tid = threadIdx.x;
    lh[tid] = 0;
    __syncthreads();
    int b, a, koff;
    const float* p = chunk_ptr(scores, blockIdx.x, b, a, koff);
    const float4* p4 = (const float4*)p;
    #pragma unroll
    for (int it = 0; it < CHUNK / 1024; ++it) {
        float4 v = p4[it * 256 + tid];
        hist_add(lh, key_bits(v.x) >> 24);
        hist_add(lh, key_bits(v.y) >> 24);
        hist_add(lh, key_bits(v.z) >> 24);
        hist_add(lh, key_bits(v.w) >> 24);
    }
    __syncthreads();
    if (lh[tid]) atomicAdd(&histA[b * 256 + tid], lh[tid]);
}

// --- Pass 1b: top-8 threshold digit ------------------------------------------
__global__ void scanA_kernel(const unsigned* __restrict__ histA,
                             unsigned* __restrict__ d8,
                             unsigned* __restrict__ aboveA) {
    int b = blockIdx.x;
    __shared__ unsigned h[256];
    h[threadIdx.x] = histA[b * 256 + threadIdx.x];
    __syncthreads();
    if (threadIdx.x == 0) {
        unsigned acc = 0; int d = 0;
        for (int i = 255; i >= 0; --i) {
            unsigned v = h[i];
            if (acc + v >= PRE_NMS) { d = i; break; }
            acc += v;
        }
        d8[b] = (unsigned)d;
        aboveA[b] = acc;
    }
}

// --- Pass 2a: refine next 8 bits among values with top-8 == d8 ---------------
__global__ __launch_bounds__(256) void histB_kernel(const float* __restrict__ scores,
                                                    const unsigned* __restrict__ d8,
                                                    unsigned* __restrict__ histB) {
    __shared__ unsigned lh[256];
    int tid = threadIdx.x;
    lh[tid] = 0;
    __syncthreads();
    int b, a, koff;
    const float* p = chunk_ptr(scores, blockIdx.x, b, a, koff);
    unsigned d = d8[b];
    const float4* p4 = (const float4*)p;
    #pragma unroll
    for (int it = 0; it < CHUNK / 1024; ++it) {
        float4 v = p4[it * 256 + tid];
        unsigned u0 = key_bits(v.x), u1 = key_bits(v.y);
        unsigned u2 = key_bits(v.z), u3 = key_bits(v.w);
        if ((u0 >> 24) == d) hist_add(lh, (u0 >> 16) & 0xFF);
        if ((u1 >> 24) == d) hist_add(lh, (u1 >> 16) & 0xFF);
        if ((u2 >> 24) == d) hist_add(lh, (u2 >> 16) & 0xFF);
        if ((u3 >> 24) == d) hist_add(lh, (u3 >> 16) & 0xFF);
    }
    __syncthreads();
    if (lh[tid]) atomicAdd(&histB[b * 256 + tid], lh[tid]);
}

// --- Pass 2b: final 16-bit thresholds (6000-target and fast 700-target) ------
__global__ void scanB_kernel(const unsigned* __restrict__ histB,
                             const unsigned* __restrict__ d8,
                             const unsigned* __restrict__ aboveA,
                             unsigned* __restrict__ tbin,
                             unsigned* __restrict__ tbin2) {
    int b = blockIdx.x;
    __shared__ unsigned h[256];
    h[threadIdx.x] = histB[b * 256 + threadIdx.x];
    __syncthreads();
    if (threadIdx.x == 0) {
        unsigned dd = d8[b];
        unsigned acc = aboveA[b];
        unsigned t2 = 0; bool t2set = false;
        if (acc >= T2TGT) { t2 = (dd + 1) << 8; t2set = true; }
        int d = 0;
        for (int i = 255; i >= 0; --i) {
            unsigned v = h[i];
            if (!t2set && acc + v >= T2TGT) { t2 = (dd << 8) | (unsigned)i; t2set = true; }
            if (acc + v >= PRE_NMS) { d = i; break; }
            acc += v;
        }
        tbin[b] = (dd << 8) | (unsigned)d;
        tbin2[b] = t2set ? t2 : ((dd << 8) | (unsigned)d);
    }
}

// --- Pass 3: compact candidates >= tbin (LDS staged, 1 global atomic/block) --
__global__ __launch_bounds__(256) void compact_kernel(
        const float* __restrict__ scores,
        const unsigned* __restrict__ tbin,
        unsigned* __restrict__ cntpad,
        unsigned long long* __restrict__ cand) {
    __shared__ unsigned long long sbuf[SBUF_CAP];
    __shared__ unsigned scount, sbase;
    int tid = threadIdx.x;
    if (tid == 0) scount = 0;
    __syncthreads();
    int b, a, koff;
    const float* p = chunk_ptr(scores, blockIdx.x, b, a, koff);
    unsigned t = tbin[b];
    const float4* p4 = (const float4*)p;
    #pragma unroll
    for (int it = 0; it < CHUNK / 1024; ++it) {
        float4 v = p4[it * 256 + tid];
        unsigned e0 = (unsigned)(koff + (it * 256 + tid) * 4);
        float vv[4] = {v.x, v.y, v.z, v.w};
        #pragma unroll
        for (int j = 0; j < 4; ++j) {
            unsigned ub = key_bits(vv[j]);
            if ((ub >> 16) >= t) {
                unsigned n = (e0 + j) * A_NUM + a;
                unsigned pos = atomicAdd(&scount, 1u);
                if (pos < SBUF_CAP)
                    sbuf[pos] = ((unsigned long long)ub << 32) | (unsigned)(~n);
            }
        }
    }
    __syncthreads();
    unsigned c = scount < SBUF_CAP ? scount : SBUF_CAP;
    if (tid == 0) sbase = atomicAdd(&cntpad[b << 5], c);
    __syncthreads();
    unsigned gb = sbase;
    for (unsigned i = tid; i < c; i += 256) {
        unsigned pos = gb + i;
        if (pos < CAP) cand[(size_t)b * CAP + pos] = sbuf[i];
    }
}

// --- Pass 4: filter >= tbin2, bitonic sort 2048, decode -> global boxes ------
__global__ __launch_bounds__(512) void sort_kernel(
        const unsigned long long* __restrict__ cand,
        const unsigned* __restrict__ cntpad,
        const unsigned* __restrict__ tbin2,
        const float* __restrict__ deltas,
        const float* __restrict__ im_info,
        float4* __restrict__ bxg,
        unsigned* __restrict__ m2arr,
        unsigned* __restrict__ okarr) {
    int b = blockIdx.x;
    __shared__ unsigned long long keys[SORT2];   // 16 KB
    __shared__ unsigned lcnt;
    int tid = threadIdx.x;
    if (tid == 0) lcnt = 0;
    for (int i = tid; i < SORT2; i += 512) keys[i] = 0ULL;
    __syncthreads();

    unsigned m = cntpad[b << 5];
    if (m > CAP) m = CAP;
    unsigned t2 = tbin2[b];
    for (unsigned i = tid; i < m; i += 512) {
        unsigned long long k64 = cand[(size_t)b * CAP + i];
        if ((unsigned)(k64 >> 48) >= t2) {
            unsigned pos = atomicAdd(&lcnt, 1u);
            if (pos < SORT2) keys[pos] = k64;
        }
    }
    __syncthreads();
    unsigned raw2 = lcnt;
    bool ok = (raw2 <= SORT2);
    unsigned m2 = raw2 > SORT2 ? SORT2 : raw2;

    for (unsigned k = 2; k <= SORT2; k <<= 1) {
        for (unsigned j = k >> 1; j > 0; j >>= 1) {
            #pragma unroll
            for (int pp = 0; pp < 2; ++pp) {
                unsigned p = (unsigned)tid + (unsigned)pp * 512u;
                unsigned i = ((p & ~(j - 1)) << 1) | (p & (j - 1));
                unsigned ixj = i | j;
                unsigned long long x = keys[i], y = keys[ixj];
                bool desc = ((i & k) == 0);
                if (desc ? (x < y) : (x > y)) { keys[i] = y; keys[ixj] = x; }
            }
            __syncthreads();
        }
    }

    float wmax = im_info[b * 3 + 1] - 1.0f;
    float hmax = im_info[b * 3 + 0] - 1.0f;
    for (unsigned i = tid; i < m2; i += 512) {
        unsigned n = ~(unsigned)(keys[i] & 0xFFFFFFFFull);
        bxg[(size_t)b * SORT2 + i] = decode_box(n, deltas, b, wmax, hmax);
    }
    if (tid == 0) { m2arr[b] = m2; okarr[b] = ok ? 1u : 0u; }
}

// --- Pass 5: forward suppression bit-matrix (fully parallel) -----------------
// Block (b, t): rows [64t, 64t+64), words w in [t+1, 32). Bit j of word w:
// IoU(row, 64w+j) > 0.7. Diagonal/backward words unwritten (never consumed).
__global__ __launch_bounds__(256) void mask_kernel(
        const float4* __restrict__ bxg,
        const unsigned* __restrict__ m2arr,
        const unsigned* __restrict__ okarr,
        unsigned long long* __restrict__ mask) {
    int b = blockIdx.x >> 5;
    int t = blockIdx.x & 31;
    if (!okarr[b]) return;
    unsigned m2 = m2arr[b];
    if ((unsigned)(t * 64) >= m2) return;
    __shared__ float4 sb[SORT2];   // 32 KB
    __shared__ float  sa[SORT2];   //  8 KB
    int tid = threadIdx.x;
    int mceil = (int)((m2 + 63u) & ~63u);
    for (int i = tid; i < mceil; i += 256) {
        float4 v = (i < (int)m2) ? bxg[(size_t)b * SORT2 + i]
                                 : make_float4(-3e9f, -3e9f, -3e9f, -3e9f);
        sb[i] = v;
        sa[i] = (v.z - v.x + 1.f) * (v.w - v.y + 1.f);
    }
    __syncthreads();
    int r = t * 64 + (tid >> 2);
    int q = tid & 3;
    float4 rb = sb[r];
    float  ra = sa[r];
    unsigned long long* mrow = mask + ((size_t)b * SORT2 + r) * NWORD;
    for (int w = t + 1 + q; w < NWORD; w += 4) {
        if (w * 64 >= mceil) break;
        unsigned long long bits = 0;
        #pragma unroll 4
        for (int jj = 0; jj < 64; ++jj) {
            int j = w * 64 + jj;
            bits |= ((unsigned long long)(iou_over(rb, ra, sb[j], sa[j]) ? 1 : 0)) << jj;
        }
        mrow[w] = bits;
    }
}

// --- Pass 6: greedy resolve via precomputed masks (1 wave per batch) ---------
__global__ __launch_bounds__(64) void resolve_kernel(
        const float4* __restrict__ bxg,
        const unsigned long long* __restrict__ mask,
        const unsigned* __restrict__ m2arr,
        const unsigned* __restrict__ okarr,
        float* __restrict__ out,
        unsigned* __restrict__ need_full) {
    int b = blockIdx.x;
    int lane = threadIdx.x;
    if (!okarr[b]) { if (lane == 0) need_full[b] = 1u; return; }
    int m2 = (int)m2arr[b];
    __shared__ unsigned short kept_idx[POST_NMS];
    const float4* bx = bxg + (size_t)b * SORT2;
    const unsigned long long* mb = mask + (size_t)b * SORT2 * NWORD;
    unsigned long long S = 0;   // lane l (<32) owns suppressed-word l
    int nk = 0;
    for (int c = 0; c < NWORD && c * 64 < m2 && nk < POST_NMS; ++c) {
        int nvalid = min(64, m2 - c * 64);
        float4 box = bx[c * 64 + (lane < nvalid ? lane : 0)];
        float area = (box.z - box.x + 1.f) * (box.w - box.y + 1.f);
        unsigned long long Sc = __shfl(S, c);            // uniform
        unsigned long long live = ~Sc;
        if (nvalid < 64) live &= ((1ull << nvalid) - 1ull);
        unsigned long long keptC = 0;
        while (live && nk < POST_NMS) {
            int il = (int)(__ffsll((long long)live) - 1); // uniform
            float bix = __shfl(box.x, il), biy = __shfl(box.y, il);
            float biz = __shfl(box.z, il), biw = __shfl(box.w, il);
            float bia = __shfl(area, il);
            bool sup = (lane < nvalid) &&
                       iou_over(make_float4(bix, biy, biz, biw), bia, box, area);
            unsigned long long bal = __ballot(sup) | (1ull << il);
            live &= ~bal;
            if (lane == 0) kept_idx[nk] = (unsigned short)(c * 64 + il);
            keptC |= 1ull << il;
            ++nk;
        }
        // bulk running-mask update: 4-wide grouped loads (latency overlapped)
        if (nk < POST_NMS && (c + 1) * 64 < m2 && keptC) {
            while (keptC) {
                int i0 = (int)(__ffsll((long long)keptC) - 1); keptC &= keptC - 1ull;
                int i1 = -1, i2 = -1, i3 = -1;
                if (keptC) { i1 = (int)(__ffsll((long long)keptC) - 1); keptC &= keptC - 1ull; }
                if (keptC) { i2 = (int)(__ffsll((long long)keptC) - 1); keptC &= keptC - 1ull; }
                if (keptC) { i3 = (int)(__ffsll((long long)keptC) - 1); keptC &= keptC - 1ull; }
                unsigned long long t0 = 0, t1 = 0, t2 = 0, t3 = 0;
                if (lane < NWORD) {
                    t0 = mb[(size_t)(c * 64 + i0) * NWORD + lane];
                    if (i1 >= 0) t1 = mb[(size_t)(c * 64 + i1) * NWORD + lane];
                    if (i2 >= 0) t2 = mb[(size_t)(c * 64 + i2) * NWORD + lane];
                    if (i3 >= 0) t3 = mb[(size_t)(c * 64 + i3) * NWORD + lane];
                }
                S |= t0 | t1 | t2 | t3;
            }
        }
    }
    __syncthreads();
    if (lane == 0) need_full[b] = (nk < POST_NMS) ? 1u : 0u;
    for (int t = lane; t < nk; t += 64) {
        float4 kb = bx[kept_idx[t]];
        float* o = out + ((size_t)b * POST_NMS + t) * 5;
        o[0] = (float)b;
        o[1] = kb.x; o[2] = kb.y; o[3] = kb.z; o[4] = kb.w;
    }
    for (int t = nk + lane; t < POST_NMS; t += 64) {
        float* o = out + ((size_t)b * POST_NMS + t) * 5;
        o[0] = (float)b;
        o[1] = 0.f; o[2] = 0.f; o[3] = 0.f; o[4] = 0.f;
    }
}

// --- Legacy fused fast path (used only if workspace too small for masks) -----
__global__ __launch_bounds__(512) void topk_nms_kernel(
        const unsigned long long* __restrict__ cand,
        const unsigned* __restrict__ cntpad,
        const unsigned* __restrict__ tbin2,
        const float* __restrict__ deltas,
        const float* __restrict__ im_info,
        float* __restrict__ out,
        unsigned* __restrict__ need_full) {
    int b = blockIdx.x;
    __shared__ unsigned long long keys[SORT2];
    __shared__ float4 bx[SORT2];
    __shared__ float4 kept_s[POST_NMS];
    __shared__ float karea_s[POST_NMS];
    __shared__ unsigned lcnt;
    int tid = threadIdx.x;
    if (tid == 0) lcnt = 0;
    for (int i = tid; i < SORT2; i += 512) keys[i] = 0ULL;
    __syncthreads();
    unsigned m = cntpad[b << 5];
    if (m > CAP) m = CAP;
    unsigned t2 = tbin2[b];
    for (unsigned i = tid; i < m; i += 512) {
        unsigned long long k64 = cand[(size_t)b * CAP + i];
        if ((unsigned)(k64 >> 48) >= t2) {
            unsigned pos = atomicAdd(&lcnt, 1u);
            if (pos < SORT2) keys[pos] = k64;
        }
    }
    __syncthreads();
    unsigned raw2 = lcnt;
    bool ok = (raw2 <= SORT2);
    unsigned m2 = raw2 > SORT2 ? SORT2 : raw2;
    for (unsigned k = 2; k <= SORT2; k <<= 1) {
        for (unsigned j = k >> 1; j > 0; j >>= 1) {
            #pragma unroll
            for (int pp = 0; pp < 2; ++pp) {
                unsigned p = (unsigned)tid + (unsigned)pp * 512u;
                unsigned i = ((p & ~(j - 1)) << 1) | (p & (j - 1));
                unsigned ixj = i | j;
                unsigned long long x = keys[i], y = keys[ixj];
                bool desc = ((i & k) == 0);
                if (desc ? (x < y) : (x > y)) { keys[i] = y; keys[ixj] = x; }
            }
            __syncthreads();
        }
    }
    float wmax = im_info[b * 3 + 1] - 1.0f;
    float hmax = im_info[b * 3 + 0] - 1.0f;
    for (unsigned i = tid; i < m2; i += 512) {
        unsigned n = ~(unsigned)(keys[i] & 0xFFFFFFFFull);
        bx[i] = decode_box(n, deltas, b, wmax, hmax);
    }
    __syncthreads();
    if (tid >= 64) return;
    int lane = tid;
    if (!ok) { if (lane == 0) need_full[b] = 1u; return; }
    int nk = 0;
    for (int i = 0; i < (int)m2 && nk < POST_NMS; ++i) {
        float4 cur = bx[i];
        float ca = (cur.z - cur.x + 1.f) * (cur.w - cur.y + 1.f);
        bool sup = false;
        for (int s = lane; s < nk; s += 64)
            sup |= iou_over(kept_s[s], karea_s[s], cur, ca);
        if (!__any(sup)) {
            if (lane == 0) {
                kept_s[nk] = cur; karea_s[nk] = ca;
                float* o = out + ((size_t)b * POST_NMS + nk) * 5;
                o[0] = (float)b;
                o[1] = cur.x; o[2] = cur.y; o[3] = cur.z; o[4] = cur.w;
            }
            ++nk;
        }
    }
    if (lane == 0) need_full[b] = (nk < POST_NMS) ? 1u : 0u;
    for (int t = nk + lane; t < POST_NMS; t += 64) {
        float* o = out + ((size_t)b * POST_NMS + t) * 5;
        o[0] = (float)b;
        o[1] = 0.f; o[2] = 0.f; o[3] = 0.f; o[4] = 0.f;
    }
}

// --- Fallback A: full 8192 bitonic sort + decode (gated, normally no-op) -----
__global__ __launch_bounds__(512) void fb_sort_kernel(
        const unsigned long long* __restrict__ cand,
        const unsigned* __restrict__ cntpad,
        const unsigned* __restrict__ need_full,
        const float* __restrict__ deltas,
        const float* __restrict__ im_info,
        float4* __restrict__ boxes) {
    int b = blockIdx.x;
    if (!need_full[b]) return;
    __shared__ unsigned long long keys[CAP];
    unsigned m = cntpad[b << 5];
    if (m > CAP) m = CAP;
    for (int i = threadIdx.x; i < CAP; i += 512)
        keys[i] = (i < (int)m) ? cand[(size_t)b * CAP + i] : 0ULL;
    __syncthreads();
    for (unsigned k = 2; k <= CAP; k <<= 1) {
        for (unsigned j = k >> 1; j > 0; j >>= 1) {
            #pragma unroll
            for (int pp = 0; pp < 8; ++pp) {
                unsigned p = (unsigned)threadIdx.x + (unsigned)pp * 512u;
                unsigned i = ((p & ~(j - 1)) << 1) | (p & (j - 1));
                unsigned ixj = i | j;
                unsigned long long x = keys[i], y = keys[ixj];
                bool desc = ((i & k) == 0);
                if (desc ? (x < y) : (x > y)) { keys[i] = y; keys[ixj] = x; }
            }
            __syncthreads();
        }
    }
    float wmax = im_info[b * 3 + 1] - 1.0f;
    float hmax = im_info[b * 3 + 0] - 1.0f;
    for (int i = threadIdx.x; i < PRE_NMS; i += 512) {
        unsigned n = ~(unsigned)(keys[i] & 0xFFFFFFFFull);
        float4 box = make_float4(0.f, 0.f, 0.f, 0.f);
        if (n < N_ANCH) box = decode_box(n, deltas, b, wmax, hmax);
        boxes[(size_t)b * PRE_NMS + i] = box;
    }
}

// --- Fallback B: full NMS over 6000 (gated, normally no-op) ------------------
__global__ __launch_bounds__(64) void fb_nms_kernel(const float4* __restrict__ boxes,
                                                    const unsigned* __restrict__ need_full,
                                                    float* __restrict__ out) {
    int b = blockIdx.x;
    if (!need_full[b]) return;
    int lane = threadIdx.x;
    __shared__ float4 cbuf[64];
    __shared__ float4 kept[POST_NMS];
    __shared__ float karea[POST_NMS];
    const float4* bb = boxes + (size_t)b * PRE_NMS;
    int nk = 0;
    for (int base = 0; base < PRE_NMS && nk < POST_NMS; base += 64) {
        if (base + lane < PRE_NMS) cbuf[lane] = bb[base + lane];
        __syncthreads();
        int lim = min(64, PRE_NMS - base);
        for (int jj = 0; jj < lim; ++jj) {
            float4 cur = cbuf[jj];
            float ca = (cur.z - cur.x + 1.f) * (cur.w - cur.y + 1.f);
            bool sup = false;
            for (int s = lane; s < nk; s += 64)
                sup |= iou_over(kept[s], karea[s], cur, ca);
            if (!__any(sup)) {
                if (lane == 0) {
                    kept[nk] = cur; karea[nk] = ca;
                    float* o = out + ((size_t)b * POST_NMS + nk) * 5;
                    o[0] = (float)b;
                    o[1] = cur.x; o[2] = cur.y; o[3] = cur.z; o[4] = cur.w;
                }
                ++nk;
                if (nk >= POST_NMS) break;
            }
        }
        __syncthreads();
    }
    for (int t = nk + lane; t < POST_NMS; t += 64) {
        float* o = out + ((size_t)b * POST_NMS + t) * 5;
        o[0] = (float)b;
        o[1] = 0.f; o[2] = 0.f; o[3] = 0.f; o[4] = 0.f;
    }
}

extern "C" void kernel_launch(void* const* d_in, const int* in_sizes, int n_in,
                              void* d_out, int out_size, void* d_ws, size_t ws_size,
                              hipStream_t stream) {
    const float* scores  = (const float*)d_in[0];
    const float* deltas  = (const float*)d_in[1];
    const float* im_info = (const float*)d_in[2];
    float* out = (float*)d_out;

    unsigned* histA   = (unsigned*)d_ws;                  // 16*256
    unsigned* histB   = histA + BATCH * 256;              // 16*256
    unsigned* cntpad  = histB + BATCH * 256;              // 16*32
    unsigned* d8      = cntpad + BATCH * 32;              // 16
    unsigned* aboveA  = d8 + BATCH;                       // 16
    unsigned* tbin    = aboveA + BATCH;                   // 16
    unsigned* tbin2   = tbin + BATCH;                     // 16
    unsigned* need_fl = tbin2 + BATCH;                    // 16
    unsigned* m2arr   = need_fl + BATCH;                  // 16
    unsigned* okarr   = m2arr + BATCH;                    // 16
    size_t off = (char*)(okarr + BATCH) - (char*)d_ws;
    off = (off + 255) & ~(size_t)255;
    unsigned long long* cand = (unsigned long long*)((char*)d_ws + off);
    off += (size_t)BATCH * CAP * 8;                       // 1 MB
    off = (off + 255) & ~(size_t)255;
    float4* boxes_fb = (float4*)((char*)d_ws + off);      // 1.5 MB (fallback)
    off += (size_t)BATCH * PRE_NMS * 16;
    off = (off + 255) & ~(size_t)255;
    float4* bxg = (float4*)((char*)d_ws + off);           // 512 KB
    off += (size_t)BATCH * SORT2 * 16;
    off = (off + 255) & ~(size_t)255;
    unsigned long long* mask = (unsigned long long*)((char*)d_ws + off); // 8 MB
    size_t need = off + (size_t)BATCH * SORT2 * NWORD * 8;

    size_t zero_bytes = (size_t)(2 * BATCH * 256 + BATCH * 32) * 4;
    hipMemsetAsync(d_ws, 0, zero_bytes, stream);

    const int nblk = BATCH * BPB;   // 1296
    histA_kernel  <<<nblk, 256, 0, stream>>>(scores, histA);
    scanA_kernel  <<<BATCH, 256, 0, stream>>>(histA, d8, aboveA);
    histB_kernel  <<<nblk, 256, 0, stream>>>(scores, d8, histB);
    scanB_kernel  <<<BATCH, 256, 0, stream>>>(histB, d8, aboveA, tbin, tbin2);
    compact_kernel<<<nblk, 256, 0, stream>>>(scores, tbin, cntpad, cand);

    if (ws_size >= need) {
        sort_kernel   <<<BATCH, 512, 0, stream>>>(cand, cntpad, tbin2, deltas, im_info,
                                                  bxg, m2arr, okarr);
        mask_kernel   <<<BATCH * 32, 256, 0, stream>>>(bxg, m2arr, okarr, mask);
        resolve_kernel<<<BATCH, 64, 0, stream>>>(bxg, mask, m2arr, okarr, out, need_fl);
    } else {
        topk_nms_kernel<<<BATCH, 512, 0, stream>>>(cand, cntpad, tbin2, deltas, im_info,
                                                   out, need_fl);
    }
    fb_sort_kernel<<<BATCH, 512, 0, stream>>>(cand, cntpad, need_fl, deltas, im_info, boxes_fb);
    fb_nms_kernel <<<BATCH, 64, 0, stream>>>(boxes_fb, need_fl, out);
}

// Round 6
// 175.829 us; speedup vs baseline: 18.3306x; 1.2269x over previous
//
#include <hip/hip_runtime.h>
#include <stdint.h>

// Problem constants (fixed by setup_inputs: B=16, A=9, H=W=192)
#define A_NUM    9
#define W_FEAT   192
#define H_FEAT   192
#define K_FEAT   (W_FEAT * H_FEAT)     // 36864 positions
#define N_ANCH   (K_FEAT * A_NUM)      // 331776 anchors per batch
#define BATCH    16
#define PRE_NMS  6000
#define POST_NMS 300
#define CAP      8192                  // full candidate buffer (above tbin)
#define CHUNK    4096                  // elements per block for hist/compact
#define BPB      (N_ANCH / CHUNK)      // 81 blocks per batch
#define CPA      (K_FEAT / CHUNK)      // 9 chunks per anchor-plane
#define SBUF_CAP 1024                  // per-block candidate staging (mean ~91)
#define T2TGT    700                   // fast-path candidate target
#define SORT2    2048                  // fast-path sort size (m2 <= ~2000)
#define NWORD    (SORT2 / 64)          // 32 mask words per row

// LDS bank swizzle for the sort arrays (b32 elements)
#define SIDX(i) ((unsigned)(i) ^ ((((unsigned)(i)) >> 5) & 31u))

// py-faster-rcnn standard anchors (base 16, ratios .5/1/2, scales 8/16/32)
__constant__ float c_anchors[A_NUM][4] = {
    { -84.f,  -40.f,  99.f,  55.f},
    {-176.f,  -88.f, 191.f, 103.f},
    {-360.f, -184.f, 375.f, 199.f},
    { -56.f,  -56.f,  71.f,  71.f},
    {-120.f, -120.f, 135.f, 135.f},
    {-248.f, -248.f, 263.f, 263.f},
    { -36.f,  -80.f,  51.f,  95.f},
    { -80.f, -168.f,  95.f, 183.f},
    {-168.f, -344.f, 183.f, 359.f},
};

__device__ __forceinline__ unsigned key_bits(float s) {
    unsigned ub = __float_as_uint(s);
    return (ub & 0x80000000u) ? ~ub : (ub | 0x80000000u);
}

__device__ __forceinline__ const float* chunk_ptr(const float* scores, int blk,
                                                  int& b, int& a, int& koff) {
    b = blk / BPB;
    int chunk = blk - b * BPB;
    a = chunk / CPA;
    koff = (chunk - a * CPA) * CHUNK;
    return scores + ((size_t)(b * 2 * A_NUM + A_NUM + a)) * K_FEAT + koff;
}

// ballot-aggregated LDS histogram add: one atomic per distinct bin per wave
__device__ __forceinline__ void hist_add(unsigned* lh, unsigned bin) {
    unsigned long long peers = __ballot(1);
    #pragma unroll
    for (int bit = 0; bit < 8; ++bit) {
        unsigned long long vote = __ballot((bin >> bit) & 1);
        peers &= ((bin >> bit) & 1) ? vote : ~vote;
    }
    int lane = threadIdx.x & 63;
    if (lane == (int)(__ffsll((long long)peers) - 1))
        atomicAdd(&lh[bin], (unsigned)__popcll(peers));
}

__device__ __forceinline__ float4 decode_box(unsigned n, const float* __restrict__ deltas,
                                             int b, float wmax, float hmax) {
    unsigned kk = n / A_NUM, a = n - kk * A_NUM;
    unsigned hh = kk / W_FEAT, ww = kk - hh * W_FEAT;
    size_t dbase = ((size_t)(b * 4 * A_NUM + 4 * a)) * K_FEAT + kk;
    float dx = deltas[dbase];
    float dy = deltas[dbase + (size_t)K_FEAT];
    float dw = deltas[dbase + (size_t)2 * K_FEAT];
    float dh = deltas[dbase + (size_t)3 * K_FEAT];
    float ax1 = c_anchors[a][0] + ww * 16.0f;
    float ay1 = c_anchors[a][1] + hh * 16.0f;
    float ax2 = c_anchors[a][2] + ww * 16.0f;
    float ay2 = c_anchors[a][3] + hh * 16.0f;
    float waf = ax2 - ax1 + 1.0f, haf = ay2 - ay1 + 1.0f;
    float cx = ax1 + 0.5f * waf, cy = ay1 + 0.5f * haf;
    float pcx = dx * waf + cx, pcy = dy * haf + cy;
    float pw = expf(dw) * waf, ph = expf(dh) * haf;
    float4 box;
    box.x = fminf(fmaxf(pcx - 0.5f * pw, 0.f), wmax);
    box.y = fminf(fmaxf(pcy - 0.5f * ph, 0.f), hmax);
    box.z = fminf(fmaxf(pcx + 0.5f * pw, 0.f), wmax);
    box.w = fminf(fmaxf(pcy + 0.5f * ph, 0.f), hmax);
    return box;
}

// IoU(a, c) > 0.7 — identical algebra in every consumer (bit-identical decisions)
__device__ __forceinline__ bool iou_over(float4 a, float aa, float4 c, float ca) {
    float xx1 = fmaxf(a.x, c.x), yy1 = fmaxf(a.y, c.y);
    float xx2 = fminf(a.z, c.z), yy2 = fminf(a.w, c.w);
    float iw = fmaxf(xx2 - xx1 + 1.f, 0.f);
    float ih = fmaxf(yy2 - yy1 + 1.f, 0.f);
    float inter = iw * ih;
    return inter > 0.7f * (aa + ca - inter);
}

// --- Pass 1a: per-batch 256-bin histogram of top-8 key bits ------------------
__global__ __launch_bounds__(256) void histA_kernel(const float* __restrict__ scores,
                                                    unsigned* __restrict__ histA) {
    __shared__ unsigned lh[256];
    int tid = threadIdx.x;
    lh[tid] = 0;
    __syncthreads();
    int b, a, koff;
    const float* p = chunk_ptr(scores, blockIdx.x, b, a, koff);
    const float4* p4 = (const float4*)p;
    #pragma unroll
    for (int it = 0; it < CHUNK / 1024; ++it) {
        float4 v = p4[it * 256 + tid];
        hist_add(lh, key_bits(v.x) >> 24);
        hist_add(lh, key_bits(v.y) >> 24);
        hist_add(lh, key_bits(v.z) >> 24);
        hist_add(lh, key_bits(v.w) >> 24);
    }
    __syncthreads();
    if (lh[tid]) atomicAdd(&histA[b * 256 + tid], lh[tid]);
}

// --- Pass 1b: top-8 threshold digit ------------------------------------------
__global__ void scanA_kernel(const unsigned* __restrict__ histA,
                             unsigned* __restrict__ d8,
                             unsigned* __restrict__ aboveA) {
    int b = blockIdx.x;
    __shared__ unsigned h[256];
    h[threadIdx.x] = histA[b * 256 + threadIdx.x];
    __syncthreads();
    if (threadIdx.x == 0) {
        unsigned acc = 0; int d = 0;
        for (int i = 255; i >= 0; --i) {
            unsigned v = h[i];
            if (acc + v >= PRE_NMS) { d = i; break; }
            acc += v;
        }
        d8[b] = (unsigned)d;
        aboveA[b] = acc;
    }
}

// --- Pass 2a: refine next 8 bits among values with top-8 == d8 ---------------
__global__ __launch_bounds__(256) void histB_kernel(const float* __restrict__ scores,
                                                    const unsigned* __restrict__ d8,
                                                    unsigned* __restrict__ histB) {
    __shared__ unsigned lh[256];
    int tid = threadIdx.x;
    lh[tid] = 0;
    __syncthreads();
    int b, a, koff;
    const float* p = chunk_ptr(scores, blockIdx.x, b, a, koff);
    unsigned d = d8[b];
    const float4* p4 = (const float4*)p;
    #pragma unroll
    for (int it = 0; it < CHUNK / 1024; ++it) {
        float4 v = p4[it * 256 + tid];
        unsigned u0 = key_bits(v.x), u1 = key_bits(v.y);
        unsigned u2 = key_bits(v.z), u3 = key_bits(v.w);
        if ((u0 >> 24) == d) hist_add(lh, (u0 >> 16) & 0xFF);
        if ((u1 >> 24) == d) hist_add(lh, (u1 >> 16) & 0xFF);
        if ((u2 >> 24) == d) hist_add(lh, (u2 >> 16) & 0xFF);
        if ((u3 >> 24) == d) hist_add(lh, (u3 >> 16) & 0xFF);
    }
    __syncthreads();
    if (lh[tid]) atomicAdd(&histB[b * 256 + tid], lh[tid]);
}

// --- Pass 2b: final 16-bit thresholds (6000-target and fast 700-target) ------
__global__ void scanB_kernel(const unsigned* __restrict__ histB,
                             const unsigned* __restrict__ d8,
                             const unsigned* __restrict__ aboveA,
                             unsigned* __restrict__ tbin,
                             unsigned* __restrict__ tbin2) {
    int b = blockIdx.x;
    __shared__ unsigned h[256];
    h[threadIdx.x] = histB[b * 256 + threadIdx.x];
    __syncthreads();
    if (threadIdx.x == 0) {
        unsigned dd = d8[b];
        unsigned acc = aboveA[b];
        unsigned t2 = 0; bool t2set = false;
        if (acc >= T2TGT) { t2 = (dd + 1) << 8; t2set = true; }
        int d = 0;
        for (int i = 255; i >= 0; --i) {
            unsigned v = h[i];
            if (!t2set && acc + v >= T2TGT) { t2 = (dd << 8) | (unsigned)i; t2set = true; }
            if (acc + v >= PRE_NMS) { d = i; break; }
            acc += v;
        }
        tbin[b] = (dd << 8) | (unsigned)d;
        tbin2[b] = t2set ? t2 : ((dd << 8) | (unsigned)d);
    }
}

// --- Pass 3: compact candidates >= tbin (LDS staged, 1 global atomic/block) --
__global__ __launch_bounds__(256) void compact_kernel(
        const float* __restrict__ scores,
        const unsigned* __restrict__ tbin,
        unsigned* __restrict__ cntpad,
        unsigned long long* __restrict__ cand) {
    __shared__ unsigned long long sbuf[SBUF_CAP];
    __shared__ unsigned scount, sbase;
    int tid = threadIdx.x;
    if (tid == 0) scount = 0;
    __syncthreads();
    int b, a, koff;
    const float* p = chunk_ptr(scores, blockIdx.x, b, a, koff);
    unsigned t = tbin[b];
    const float4* p4 = (const float4*)p;
    #pragma unroll
    for (int it = 0; it < CHUNK / 1024; ++it) {
        float4 v = p4[it * 256 + tid];
        unsigned e0 = (unsigned)(koff + (it * 256 + tid) * 4);
        float vv[4] = {v.x, v.y, v.z, v.w};
        #pragma unroll
        for (int j = 0; j < 4; ++j) {
            unsigned ub = key_bits(vv[j]);
            if ((ub >> 16) >= t) {
                unsigned n = (e0 + j) * A_NUM + a;
                unsigned pos = atomicAdd(&scount, 1u);
                if (pos < SBUF_CAP)
                    sbuf[pos] = ((unsigned long long)ub << 32) | (unsigned)(~n);
            }
        }
    }
    __syncthreads();
    unsigned c = scount < SBUF_CAP ? scount : SBUF_CAP;
    if (tid == 0) sbase = atomicAdd(&cntpad[b << 5], c);
    __syncthreads();
    unsigned gb = sbase;
    for (unsigned i = tid; i < c; i += 256) {
        unsigned pos = gb + i;
        if (pos < CAP) cand[(size_t)b * CAP + pos] = sbuf[i];
    }
}

// --- Pass 4: filter >= tbin2, bitonic sort 2048 (SoA u32 + swizzle), decode --
__global__ __launch_bounds__(512) void sort_kernel(
        const unsigned long long* __restrict__ cand,
        const unsigned* __restrict__ cntpad,
        const unsigned* __restrict__ tbin2,
        const float* __restrict__ deltas,
        const float* __restrict__ im_info,
        float4* __restrict__ bxg,
        unsigned* __restrict__ m2arr,
        unsigned* __restrict__ okarr) {
    int b = blockIdx.x;
    __shared__ unsigned khi[SORT2];   // 8 KB
    __shared__ unsigned klo[SORT2];   // 8 KB
    __shared__ unsigned lcnt;
    int tid = threadIdx.x;
    if (tid == 0) lcnt = 0;
    for (int i = tid; i < SORT2; i += 512) { khi[SIDX(i)] = 0u; klo[SIDX(i)] = 0u; }
    __syncthreads();

    unsigned m = cntpad[b << 5];
    if (m > CAP) m = CAP;
    unsigned t2 = tbin2[b];
    for (unsigned i = tid; i < m; i += 512) {
        unsigned long long k64 = cand[(size_t)b * CAP + i];
        if ((unsigned)(k64 >> 48) >= t2) {
            unsigned pos = atomicAdd(&lcnt, 1u);
            if (pos < SORT2) {
                khi[SIDX(pos)] = (unsigned)(k64 >> 32);
                klo[SIDX(pos)] = (unsigned)k64;
            }
        }
    }
    __syncthreads();
    unsigned raw2 = lcnt;
    bool ok = (raw2 <= SORT2);
    unsigned m2 = raw2 > SORT2 ? SORT2 : raw2;

    for (unsigned k = 2; k <= SORT2; k <<= 1) {
        for (unsigned j = k >> 1; j > 0; j >>= 1) {
            #pragma unroll
            for (int pp = 0; pp < 2; ++pp) {
                unsigned p = (unsigned)tid + (unsigned)pp * 512u;
                unsigned i = ((p & ~(j - 1)) << 1) | (p & (j - 1));
                unsigned ixj = i | j;
                unsigned ia = SIDX(i), ja = SIDX(ixj);
                unsigned xh = khi[ia], xl = klo[ia];
                unsigned yh = khi[ja], yl = klo[ja];
                unsigned long long x = ((unsigned long long)xh << 32) | xl;
                unsigned long long y = ((unsigned long long)yh << 32) | yl;
                bool desc = ((i & k) == 0);
                if (desc ? (x < y) : (x > y)) {
                    khi[ia] = yh; klo[ia] = yl;
                    khi[ja] = xh; klo[ja] = xl;
                }
            }
            __syncthreads();
        }
    }

    float wmax = im_info[b * 3 + 1] - 1.0f;
    float hmax = im_info[b * 3 + 0] - 1.0f;
    for (unsigned i = tid; i < m2; i += 512) {
        unsigned n = ~klo[SIDX(i)];
        bxg[(size_t)b * SORT2 + i] = decode_box(n, deltas, b, wmax, hmax);
    }
    if (tid == 0) { m2arr[b] = m2; okarr[b] = ok ? 1u : 0u; }
}

// --- Pass 5: suppression bit-matrix incl. DIAGONAL word (fully parallel) -----
// Block (b, t): rows [64t, 64t+64), words w in [t, 32). Bit j of word w:
// IoU(row, 64w+j) > 0.7. Backward words unwritten (never consumed).
__global__ __launch_bounds__(256) void mask_kernel(
        const float4* __restrict__ bxg,
        const unsigned* __restrict__ m2arr,
        const unsigned* __restrict__ okarr,
        unsigned long long* __restrict__ mask) {
    int b = blockIdx.x >> 5;
    int t = blockIdx.x & 31;
    if (!okarr[b]) return;
    unsigned m2 = m2arr[b];
    if ((unsigned)(t * 64) >= m2) return;
    __shared__ float4 sb[SORT2];   // 32 KB
    __shared__ float  sa[SORT2];   //  8 KB
    int tid = threadIdx.x;
    int mceil = (int)((m2 + 63u) & ~63u);
    for (int i = tid; i < mceil; i += 256) {
        float4 v = (i < (int)m2) ? bxg[(size_t)b * SORT2 + i]
                                 : make_float4(-3e9f, -3e9f, -3e9f, -3e9f);
        sb[i] = v;
        sa[i] = (v.z - v.x + 1.f) * (v.w - v.y + 1.f);
    }
    __syncthreads();
    int r = t * 64 + (tid >> 2);
    int q = tid & 3;
    float4 rb = sb[r];
    float  ra = sa[r];
    unsigned long long* mrow = mask + ((size_t)b * SORT2 + r) * NWORD;
    for (int w = t + q; w < NWORD; w += 4) {
        if (w * 64 >= mceil) break;
        unsigned long long bits = 0;
        #pragma unroll 4
        for (int jj = 0; jj < 64; ++jj) {
            int j = w * 64 + jj;
            bits |= ((unsigned long long)(iou_over(rb, ra, sb[j], sa[j]) ? 1 : 0)) << jj;
        }
        mrow[w] = bits;
    }
}

// --- Pass 6: greedy resolve — diag rows in registers, readlane broadcast -----
__global__ __launch_bounds__(64) void resolve_kernel(
        const float4* __restrict__ bxg,
        const unsigned long long* __restrict__ mask,
        const unsigned* __restrict__ m2arr,
        const unsigned* __restrict__ okarr,
        float* __restrict__ out,
        unsigned* __restrict__ need_full) {
    int b = blockIdx.x;
    int lane = threadIdx.x;
    if (!okarr[b]) { if (lane == 0) need_full[b] = 1u; return; }
    int m2 = (int)m2arr[b];
    __shared__ unsigned short kept_idx[POST_NMS];
    const float4* bx = bxg + (size_t)b * SORT2;
    const unsigned long long* mb = mask + (size_t)b * SORT2 * NWORD;
    // cross-chunk suppressed mask S: word w is (lane w accum) | (lane 32+w accum)
    unsigned long long S = 0;
    int w32 = lane & 31;
    bool hiHalf = lane >= 32;
    int nchunks = (m2 + 63) >> 6;
    // prefetch diag word for chunk 0: lane j holds row j's word 0
    unsigned long long dpre = mb[(size_t)lane * NWORD + 0];
    int nk = 0;
    for (int c = 0; c < nchunks && nk < POST_NMS; ++c) {
        int base = c * 64;
        int nvalid = min(64, m2 - base);
        unsigned long long d = dpre;
        if (c + 1 < nchunks)   // prefetch next chunk's diag (independent)
            dpre = mb[(size_t)(base + 64 + lane) * NWORD + (c + 1)];
        // live = ~(word c of S), via cheap scalar broadcasts
        unsigned wl0 = __builtin_amdgcn_readlane((unsigned)S, c);
        unsigned wh0 = __builtin_amdgcn_readlane((unsigned)(S >> 32), c);
        unsigned wl1 = __builtin_amdgcn_readlane((unsigned)S, c + 32);
        unsigned wh1 = __builtin_amdgcn_readlane((unsigned)(S >> 32), c + 32);
        unsigned long long Sc = (((unsigned long long)wh0 << 32) | wl0)
                              | (((unsigned long long)wh1 << 32) | wl1);
        unsigned long long live = ~Sc;
        if (nvalid < 64) live &= (1ull << nvalid) - 1ull;
        unsigned long long keptC = 0;
        while (live && nk < POST_NMS) {
            int il = (int)__ffsll((long long)live) - 1;     // uniform
            unsigned dlo = __builtin_amdgcn_readlane((unsigned)d, il);
            unsigned dhi = __builtin_amdgcn_readlane((unsigned)(d >> 32), il);
            unsigned long long drow = ((unsigned long long)dhi << 32) | dlo;
            live &= ~drow;
            live &= ~(1ull << il);
            if (lane == 0) kept_idx[nk] = (unsigned short)(base + il);
            keptC |= 1ull << il;
            ++nk;
        }
        // cross-chunk S update: 8 rows/round, parity-split (2 lanes per word),
        // 4 independent loads per lane -> one latency per round
        if (nk < POST_NMS && c + 1 < nchunks && keptC) {
            long long kc = (long long)keptC;
            while (kc) {
                int r0 = (int)__ffsll(kc) - 1; kc &= kc - 1;
                int r1 = (int)__ffsll(kc) - 1; kc &= kc - 1;
                int r2 = (int)__ffsll(kc) - 1; kc &= kc - 1;
                int r3 = (int)__ffsll(kc) - 1; kc &= kc - 1;
                int r4 = (int)__ffsll(kc) - 1; kc &= kc - 1;
                int r5 = (int)__ffsll(kc) - 1; kc &= kc - 1;
                int r6 = (int)__ffsll(kc) - 1; kc &= kc - 1;
                int r7 = (int)__ffsll(kc) - 1; kc &= kc - 1;
                int s0 = hiHalf ? r1 : r0;
                int s1 = hiHalf ? r3 : r2;
                int s2 = hiHalf ? r5 : r4;
                int s3 = hiHalf ? r7 : r6;
                unsigned long long a0 = 0, a1 = 0, a2 = 0, a3 = 0;
                if (s0 >= 0) a0 = mb[(size_t)(base + s0) * NWORD + w32];
                if (s1 >= 0) a1 = mb[(size_t)(base + s1) * NWORD + w32];
                if (s2 >= 0) a2 = mb[(size_t)(base + s2) * NWORD + w32];
                if (s3 >= 0) a3 = mb[(size_t)(base + s3) * NWORD + w32];
                S |= a0 | a1 | a2 | a3;
            }
        }
    }
    __syncthreads();
    if (lane == 0) need_full[b] = (nk < POST_NMS) ? 1u : 0u;
    for (int t = lane; t < nk; t += 64) {
        float4 kb = bx[kept_idx[t]];
        float* o = out + ((size_t)b * POST_NMS + t) * 5;
        o[0] = (float)b;
        o[1] = kb.x; o[2] = kb.y; o[3] = kb.z; o[4] = kb.w;
    }
    for (int t = nk + lane; t < POST_NMS; t += 64) {
        float* o = out + ((size_t)b * POST_NMS + t) * 5;
        o[0] = (float)b;
        o[1] = 0.f; o[2] = 0.f; o[3] = 0.f; o[4] = 0.f;
    }
}

// --- Legacy fused fast path (used only if workspace too small for masks) -----
__global__ __launch_bounds__(512) void topk_nms_kernel(
        const unsigned long long* __restrict__ cand,
        const unsigned* __restrict__ cntpad,
        const unsigned* __restrict__ tbin2,
        const float* __restrict__ deltas,
        const float* __restrict__ im_info,
        float* __restrict__ out,
        unsigned* __restrict__ need_full) {
    int b = blockIdx.x;
    __shared__ unsigned long long keys[SORT2];
    __shared__ float4 bx[SORT2];
    __shared__ float4 kept_s[POST_NMS];
    __shared__ float karea_s[POST_NMS];
    __shared__ unsigned lcnt;
    int tid = threadIdx.x;
    if (tid == 0) lcnt = 0;
    for (int i = tid; i < SORT2; i += 512) keys[i] = 0ULL;
    __syncthreads();
    unsigned m = cntpad[b << 5];
    if (m > CAP) m = CAP;
    unsigned t2 = tbin2[b];
    for (unsigned i = tid; i < m; i += 512) {
        unsigned long long k64 = cand[(size_t)b * CAP + i];
        if ((unsigned)(k64 >> 48) >= t2) {
            unsigned pos = atomicAdd(&lcnt, 1u);
            if (pos < SORT2) keys[pos] = k64;
        }
    }
    __syncthreads();
    unsigned raw2 = lcnt;
    bool ok = (raw2 <= SORT2);
    unsigned m2 = raw2 > SORT2 ? SORT2 : raw2;
    for (unsigned k = 2; k <= SORT2; k <<= 1) {
        for (unsigned j = k >> 1; j > 0; j >>= 1) {
            #pragma unroll
            for (int pp = 0; pp < 2; ++pp) {
                unsigned p = (unsigned)tid + (unsigned)pp * 512u;
                unsigned i = ((p & ~(j - 1)) << 1) | (p & (j - 1));
                unsigned ixj = i | j;
                unsigned long long x = keys[i], y = keys[ixj];
                bool desc = ((i & k) == 0);
                if (desc ? (x < y) : (x > y)) { keys[i] = y; keys[ixj] = x; }
            }
            __syncthreads();
        }
    }
    float wmax = im_info[b * 3 + 1] - 1.0f;
    float hmax = im_info[b * 3 + 0] - 1.0f;
    for (unsigned i = tid; i < m2; i += 512) {
        unsigned n = ~(unsigned)(keys[i] & 0xFFFFFFFFull);
        bx[i] = decode_box(n, deltas, b, wmax, hmax);
    }
    __syncthreads();
    if (tid >= 64) return;
    int lane = tid;
    if (!ok) { if (lane == 0) need_full[b] = 1u; return; }
    int nk = 0;
    for (int i = 0; i < (int)m2 && nk < POST_NMS; ++i) {
        float4 cur = bx[i];
        float ca = (cur.z - cur.x + 1.f) * (cur.w - cur.y + 1.f);
        bool sup = false;
        for (int s = lane; s < nk; s += 64)
            sup |= iou_over(kept_s[s], karea_s[s], cur, ca);
        if (!__any(sup)) {
            if (lane == 0) {
                kept_s[nk] = cur; karea_s[nk] = ca;
                float* o = out + ((size_t)b * POST_NMS + nk) * 5;
                o[0] = (float)b;
                o[1] = cur.x; o[2] = cur.y; o[3] = cur.z; o[4] = cur.w;
            }
            ++nk;
        }
    }
    if (lane == 0) need_full[b] = (nk < POST_NMS) ? 1u : 0u;
    for (int t = nk + lane; t < POST_NMS; t += 64) {
        float* o = out + ((size_t)b * POST_NMS + t) * 5;
        o[0] = (float)b;
        o[1] = 0.f; o[2] = 0.f; o[3] = 0.f; o[4] = 0.f;
    }
}

// --- Fallback A: full 8192 bitonic sort + decode (gated, normally no-op) -----
__global__ __launch_bounds__(512) void fb_sort_kernel(
        const unsigned long long* __restrict__ cand,
        const unsigned* __restrict__ cntpad,
        const unsigned* __restrict__ need_full,
        const float* __restrict__ deltas,
        const float* __restrict__ im_info,
        float4* __restrict__ boxes) {
    int b = blockIdx.x;
    if (!need_full[b]) return;
    __shared__ unsigned long long keys[CAP];
    unsigned m = cntpad[b << 5];
    if (m > CAP) m = CAP;
    for (int i = threadIdx.x; i < CAP; i += 512)
        keys[i] = (i < (int)m) ? cand[(size_t)b * CAP + i] : 0ULL;
    __syncthreads();
    for (unsigned k = 2; k <= CAP; k <<= 1) {
        for (unsigned j = k >> 1; j > 0; j >>= 1) {
            #pragma unroll
            for (int pp = 0; pp < 8; ++pp) {
                unsigned p = (unsigned)threadIdx.x + (unsigned)pp * 512u;
                unsigned i = ((p & ~(j - 1)) << 1) | (p & (j - 1));
                unsigned ixj = i | j;
                unsigned long long x = keys[i], y = keys[ixj];
                bool desc = ((i & k) == 0);
                if (desc ? (x < y) : (x > y)) { keys[i] = y; keys[ixj] = x; }
            }
            __syncthreads();
        }
    }
    float wmax = im_info[b * 3 + 1] - 1.0f;
    float hmax = im_info[b * 3 + 0] - 1.0f;
    for (int i = threadIdx.x; i < PRE_NMS; i += 512) {
        unsigned n = ~(unsigned)(keys[i] & 0xFFFFFFFFull);
        float4 box = make_float4(0.f, 0.f, 0.f, 0.f);
        if (n < N_ANCH) box = decode_box(n, deltas, b, wmax, hmax);
        boxes[(size_t)b * PRE_NMS + i] = box;
    }
}

// --- Fallback B: full NMS over 6000 (gated, normally no-op) ------------------
__global__ __launch_bounds__(64) void fb_nms_kernel(const float4* __restrict__ boxes,
                                                    const unsigned* __restrict__ need_full,
                                                    float* __restrict__ out) {
    int b = blockIdx.x;
    if (!need_full[b]) return;
    int lane = threadIdx.x;
    __shared__ float4 cbuf[64];
    __shared__ float4 kept[POST_NMS];
    __shared__ float karea[POST_NMS];
    const float4* bb = boxes + (size_t)b * PRE_NMS;
    int nk = 0;
    for (int base = 0; base < PRE_NMS && nk < POST_NMS; base += 64) {
        if (base + lane < PRE_NMS) cbuf[lane] = bb[base + lane];
        __syncthreads();
        int lim = min(64, PRE_NMS - base);
        for (int jj = 0; jj < lim; ++jj) {
            float4 cur = cbuf[jj];
            float ca = (cur.z - cur.x + 1.f) * (cur.w - cur.y + 1.f);
            bool sup = false;
            for (int s = lane; s < nk; s += 64)
                sup |= iou_over(kept[s], karea[s], cur, ca);
            if (!__any(sup)) {
                if (lane == 0) {
                    kept[nk] = cur; karea[nk] = ca;
                    float* o = out + ((size_t)b * POST_NMS + nk) * 5;
                    o[0] = (float)b;
                    o[1] = cur.x; o[2] = cur.y; o[3] = cur.z; o[4] = cur.w;
                }
                ++nk;
                if (nk >= POST_NMS) break;
            }
        }
        __syncthreads();
    }
    for (int t = nk + lane; t < POST_NMS; t += 64) {
        float* o = out + ((size_t)b * POST_NMS + t) * 5;
        o[0] = (float)b;
        o[1] = 0.f; o[2] = 0.f; o[3] = 0.f; o[4] = 0.f;
    }
}

extern "C" void kernel_launch(void* const* d_in, const int* in_sizes, int n_in,
                              void* d_out, int out_size, void* d_ws, size_t ws_size,
                              hipStream_t stream) {
    const float* scores  = (const float*)d_in[0];
    const float* deltas  = (const float*)d_in[1];
    const float* im_info = (const float*)d_in[2];
    float* out = (float*)d_out;

    unsigned* histA   = (unsigned*)d_ws;                  // 16*256
    unsigned* histB   = histA + BATCH * 256;              // 16*256
    unsigned* cntpad  = histB + BATCH * 256;              // 16*32
    unsigned* d8      = cntpad + BATCH * 32;              // 16
    unsigned* aboveA  = d8 + BATCH;                       // 16
    unsigned* tbin    = aboveA + BATCH;                   // 16
    unsigned* tbin2   = tbin + BATCH;                     // 16
    unsigned* need_fl = tbin2 + BATCH;                    // 16
    unsigned* m2arr   = need_fl + BATCH;                  // 16
    unsigned* okarr   = m2arr + BATCH;                    // 16
    size_t off = (char*)(okarr + BATCH) - (char*)d_ws;
    off = (off + 255) & ~(size_t)255;
    unsigned long long* cand = (unsigned long long*)((char*)d_ws + off);
    off += (size_t)BATCH * CAP * 8;                       // 1 MB
    off = (off + 255) & ~(size_t)255;
    float4* boxes_fb = (float4*)((char*)d_ws + off);      // 1.5 MB (fallback)
    off += (size_t)BATCH * PRE_NMS * 16;
    off = (off + 255) & ~(size_t)255;
    float4* bxg = (float4*)((char*)d_ws + off);           // 512 KB
    off += (size_t)BATCH * SORT2 * 16;
    off = (off + 255) & ~(size_t)255;
    unsigned long long* mask = (unsigned long long*)((char*)d_ws + off); // 8 MB
    size_t need = off + (size_t)BATCH * SORT2 * NWORD * 8;

    size_t zero_bytes = (size_t)(2 * BATCH * 256 + BATCH * 32) * 4;
    hipMemsetAsync(d_ws, 0, zero_bytes, stream);

    const int nblk = BATCH * BPB;   // 1296
    histA_kernel  <<<nblk, 256, 0, stream>>>(scores, histA);
    scanA_kernel  <<<BATCH, 256, 0, stream>>>(histA, d8, aboveA);
    histB_kernel  <<<nblk, 256, 0, stream>>>(scores, d8, histB);
    scanB_kernel  <<<BATCH, 256, 0, stream>>>(histB, d8, aboveA, tbin, tbin2);
    compact_kernel<<<nblk, 256, 0, stream>>>(scores, tbin, cntpad, cand);

    if (ws_size >= need) {
        sort_kernel   <<<BATCH, 512, 0, stream>>>(cand, cntpad, tbin2, deltas, im_info,
                                                  bxg, m2arr, okarr);
        mask_kernel   <<<BATCH * 32, 256, 0, stream>>>(bxg, m2arr, okarr, mask);
        resolve_kernel<<<BATCH, 64, 0, stream>>>(bxg, mask, m2arr, okarr, out, need_fl);
    } else {
        topk_nms_kernel<<<BATCH, 512, 0, stream>>>(cand, cntpad, tbin2, deltas, im_info,
                                                   out, need_fl);
    }
    fb_sort_kernel<<<BATCH, 512, 0, stream>>>(cand, cntpad, need_fl, deltas, im_info, boxes_fb);
    fb_nms_kernel <<<BATCH, 64, 0, stream>>>(boxes_fb, need_fl, out);
}